// Round 4
// baseline (1686.835 us; speedup 1.0000x reference)
//
#include <hip/hip_runtime.h>
#include <math.h>

// ===================== small utility kernels =====================

__global__ void k_pad(const float* __restrict__ src, int sr, int sc,
                      float* __restrict__ dst, int dr, int dc) {
  int t = blockIdx.x*blockDim.x + threadIdx.x;
  if (t >= dr*dc) return;
  int r = t/dc, c = t - r*dc;
  dst[t] = (r < sr && c < sc) ? src[r*sc + c] : 0.f;
}

__global__ void k_deg(const int* __restrict__ dst, int E, int nsl, int* __restrict__ deg) {
  int t = blockIdx.x*blockDim.x + threadIdx.x;
  if (t >= E + nsl) return;
  int d = (t < E) ? dst[t] : (t - E);
  atomicAdd(&deg[d], 1);
}

__global__ __launch_bounds__(256)
void k_scan_block(const int* __restrict__ deg, int n, int* __restrict__ out, int* __restrict__ btot) {
  __shared__ int sh[256];
  int tid = threadIdx.x;
  int base = blockIdx.x*1024 + tid*4;
  int v0 = (base+0<n)?deg[base+0]:0;
  int v1 = (base+1<n)?deg[base+1]:0;
  int v2 = (base+2<n)?deg[base+2]:0;
  int v3 = (base+3<n)?deg[base+3]:0;
  int s = v0+v1+v2+v3;
  sh[tid] = s; __syncthreads();
  for (int o = 1; o < 256; o <<= 1) {
    int t = (tid >= o) ? sh[tid-o] : 0;
    __syncthreads();
    sh[tid] += t;
    __syncthreads();
  }
  if (tid == 255) btot[blockIdx.x] = sh[255];
  int run = sh[tid] - s;
  if (base+0<n) { out[base+0]=run; run+=v0; }
  if (base+1<n) { out[base+1]=run; run+=v1; }
  if (base+2<n) { out[base+2]=run; run+=v2; }
  if (base+3<n) { out[base+3]=run; run+=v3; }
}

__global__ __launch_bounds__(512)
void k_scan_tot(int* __restrict__ btot, int nb) {
  __shared__ int sh[512];
  int tid = threadIdx.x;
  int v = (tid < nb) ? btot[tid] : 0;
  sh[tid] = v; __syncthreads();
  for (int o = 1; o < 512; o <<= 1) {
    int t = (tid >= o) ? sh[tid-o] : 0;
    __syncthreads();
    sh[tid] += t;
    __syncthreads();
  }
  if (tid < nb) btot[tid] = sh[tid] - v;
}

__global__ void k_scan_add(int* __restrict__ rowptr, const int* __restrict__ btot, int n, int total) {
  int t = blockIdx.x*blockDim.x + threadIdx.x;
  if (t < n) rowptr[t] += btot[t >> 10];
  if (t == 0) rowptr[n] = total;
}

__global__ void k_fill(const int* __restrict__ src, const int* __restrict__ dst, int E, int nsl,
                       int* __restrict__ cursor, const int* __restrict__ rowptr, int* __restrict__ csr) {
  int t = blockIdx.x*blockDim.x + threadIdx.x;
  if (t >= E + nsl) return;
  int s, d;
  if (t < E) { s = src[t]; d = dst[t]; } else { s = t - E; d = s; }
  int slot = rowptr[d] + atomicAdd(&cursor[d], 1);
  csr[slot] = s;
}

// ===================== GIN (drug) =====================
__global__ void k_gin_gather(const int* __restrict__ rowptr, const int* __restrict__ csr,
                             const float* __restrict__ x, int xs, int F,
                             float* __restrict__ xin, int ds, int n) {
  int t = blockIdx.x*blockDim.x + threadIdx.x;
  if (t >= n*ds) return;
  int d = t/ds, f = t - d*ds;
  if (f >= F) { xin[t] = 0.f; return; }
  float acc = x[(size_t)d*xs + f];
  int e1 = rowptr[d+1];
  for (int j = rowptr[d]; j < e1; ++j) acc += x[(size_t)csr[j]*xs + f];
  xin[t] = acc;
}

__global__ __launch_bounds__(384)
void k_drug_pool(const float* __restrict__ reps, float* __restrict__ xd) {
  int b = blockIdx.x, c = threadIdx.x;
  float m = -3.0e38f;
  const float* p = reps + (size_t)b*40*384 + c;
  for (int i = 0; i < 40; ++i) m = fmaxf(m, p[(size_t)i*384]);
  xd[(size_t)b*384 + c] = m;
}

// ===================== GEMM (f32, tiled 64x64, optional split-K atomics) =====================
template<int ACT, int ATOMIC>   // ACT: 0 none, 1 relu, 2 elu (non-atomic path only)
__global__ __launch_bounds__(256)
void k_gemm(const float* __restrict__ A, int lda,
            const float* __restrict__ B, int ldb,
            const float* __restrict__ bias,
            float* __restrict__ C, int ldc, int Kchunk) {
  __shared__ __align__(16) float As[32][68];
  __shared__ __align__(16) float Bs[32][68];
  const int tid = threadIdx.x;
  const int tx = tid & 15, ty = tid >> 4;
  const int row0 = blockIdx.y << 6, col0 = blockIdx.x << 6;
  const int kb = blockIdx.z * Kchunk;
  float acc[4][4] = {{0.f}};
  for (int k0 = 0; k0 < Kchunk; k0 += 32) {
#pragma unroll
    for (int i = 0; i < 2; ++i) {
      int idx = tid + (i << 8);
      int r = idx >> 3, c = (idx & 7) << 2;
      float4 v = *(const float4*)(A + (size_t)(row0 + r)*lda + (kb + k0 + c));
      As[c+0][r]=v.x; As[c+1][r]=v.y; As[c+2][r]=v.z; As[c+3][r]=v.w;
    }
#pragma unroll
    for (int i = 0; i < 2; ++i) {
      int idx = tid + (i << 8);
      int r = idx >> 4, c = (idx & 15) << 2;
      *(float4*)&Bs[r][c] = *(const float4*)(B + (size_t)(kb + k0 + r)*ldb + (col0 + c));
    }
    __syncthreads();
#pragma unroll
    for (int kk = 0; kk < 32; ++kk) {
      float4 av = *(const float4*)&As[kk][ty << 2];
      float4 bv = *(const float4*)&Bs[kk][tx << 2];
      acc[0][0]=fmaf(av.x,bv.x,acc[0][0]); acc[0][1]=fmaf(av.x,bv.y,acc[0][1]);
      acc[0][2]=fmaf(av.x,bv.z,acc[0][2]); acc[0][3]=fmaf(av.x,bv.w,acc[0][3]);
      acc[1][0]=fmaf(av.y,bv.x,acc[1][0]); acc[1][1]=fmaf(av.y,bv.y,acc[1][1]);
      acc[1][2]=fmaf(av.y,bv.z,acc[1][2]); acc[1][3]=fmaf(av.y,bv.w,acc[1][3]);
      acc[2][0]=fmaf(av.z,bv.x,acc[2][0]); acc[2][1]=fmaf(av.z,bv.y,acc[2][1]);
      acc[2][2]=fmaf(av.z,bv.z,acc[2][2]); acc[2][3]=fmaf(av.z,bv.w,acc[2][3]);
      acc[3][0]=fmaf(av.w,bv.x,acc[3][0]); acc[3][1]=fmaf(av.w,bv.y,acc[3][1]);
      acc[3][2]=fmaf(av.w,bv.z,acc[3][2]); acc[3][3]=fmaf(av.w,bv.w,acc[3][3]);
    }
    __syncthreads();
  }
  if (ATOMIC) {
#pragma unroll
    for (int i = 0; i < 4; ++i) {
      int r = row0 + (ty<<2) + i, c = col0 + (tx<<2);
#pragma unroll
      for (int j = 0; j < 4; ++j) atomicAdd(&C[(size_t)r*ldc + c + j], acc[i][j]);
    }
  } else {
#pragma unroll
    for (int i = 0; i < 4; ++i) {
      int r = row0 + (ty<<2) + i, c = col0 + (tx<<2);
      float4 v = make_float4(acc[i][0], acc[i][1], acc[i][2], acc[i][3]);
      if (bias) { v.x += bias[c]; v.y += bias[c+1]; v.z += bias[c+2]; v.w += bias[c+3]; }
      if (ACT == 1) { v.x=fmaxf(v.x,0.f); v.y=fmaxf(v.y,0.f); v.z=fmaxf(v.z,0.f); v.w=fmaxf(v.w,0.f); }
      else if (ACT == 2) {
        v.x = v.x>0.f?v.x:expm1f(v.x); v.y = v.y>0.f?v.y:expm1f(v.y);
        v.z = v.z>0.f?v.z:expm1f(v.z); v.w = v.w>0.f?v.w:expm1f(v.w);
      }
      *(float4*)(C + (size_t)r*ldc + c) = v;
    }
  }
}

template<int ACT>
__global__ void k_bias_act(float* __restrict__ C, int ldc, const float* __restrict__ bias, int M, int N) {
  int t = blockIdx.x*blockDim.x + threadIdx.x;
  if (t >= M*N) return;
  int r = t / N, c = t - r*N;
  float v = C[(size_t)r*ldc + c] + bias[c];
  if (ACT == 1) v = fmaxf(v, 0.f);
  else if (ACT == 2) v = v > 0.f ? v : expm1f(v);
  C[(size_t)r*ldc + c] = v;
}

// ===================== BatchNorm =====================
__global__ __launch_bounds__(256)
void k_bn_stats(const float* __restrict__ x, int rows, int cols, float* __restrict__ acc) {
  __shared__ float sh[256], sh2[256];
  int tid = threadIdx.x;
  int nth = gridDim.x * 256;
  int t = blockIdx.x*256 + tid;
  int c = t % cols;
  int r0 = t / cols;
  int rstep = nth / cols;
  float s = 0.f, s2 = 0.f;
  for (int r = r0; r < rows; r += rstep) {
    float v = x[(size_t)r*cols + c];
    s += v; s2 = fmaf(v, v, s2);
  }
  sh[tid] = s; sh2[tid] = s2; __syncthreads();
  for (int o = 128; o >= cols; o >>= 1) {
    if (tid < o) { sh[tid] += sh[tid+o]; sh2[tid] += sh2[tid+o]; }
    __syncthreads();
  }
  if (tid < cols) { atomicAdd(&acc[tid], sh[tid]); atomicAdd(&acc[cols+tid], sh2[tid]); }
}

__global__ void k_bn_apply(const float* __restrict__ x, int xs,
                           float* __restrict__ y, int ys,
                           const float* __restrict__ acc, float invn,
                           const float* __restrict__ g, const float* __restrict__ be,
                           int total, int cols) {
  int t = blockIdx.x*blockDim.x + threadIdx.x;
  if (t >= total) return;
  int c = t % cols;
  int r = t / cols;
  float mu = acc[c] * invn;
  float var = fmaxf(acc[cols+c]*invn - mu*mu, 0.f);
  float rstd = rsqrtf(var + 1e-5f);
  float v = (x[(size_t)r*xs + c] - mu) * rstd;
  if (g) v = fmaf(v, g[c], be[c]);
  y[(size_t)r*ys + c] = v;
}

// ===================== GAT =====================
__global__ void k_gat_node(const float* __restrict__ x, int K,
                           const float* __restrict__ W,
                           const float* __restrict__ as_, const float* __restrict__ ad_,
                           float* __restrict__ h, float* __restrict__ ssrc, float* __restrict__ sdst,
                           int n) {
  int i = blockIdx.x*blockDim.x + threadIdx.x;
  if (i >= n) return;
  float hv[16];
#pragma unroll
  for (int k = 0; k < 16; ++k) hv[k] = 0.f;
  for (int j = 0; j < K; ++j) {
    float xv = x[(size_t)i*K + j];
#pragma unroll
    for (int k = 0; k < 16; ++k) hv[k] = fmaf(xv, W[j*16 + k], hv[k]);
  }
  float s1 = 0.f, s2 = 0.f;
#pragma unroll
  for (int k = 0; k < 16; ++k) { s1 = fmaf(hv[k], as_[k], s1); s2 = fmaf(hv[k], ad_[k], s2); }
  float4* hp = (float4*)(h + (size_t)i*16);
  hp[0] = make_float4(hv[0],hv[1],hv[2],hv[3]);
  hp[1] = make_float4(hv[4],hv[5],hv[6],hv[7]);
  hp[2] = make_float4(hv[8],hv[9],hv[10],hv[11]);
  hp[3] = make_float4(hv[12],hv[13],hv[14],hv[15]);
  ssrc[i] = s1; sdst[i] = s2;
}

// Edge-parallel scatter aggregation: 16 lanes per edge (incl. self-loops at
// g>=E). Replaces CSR build (315MB of scattered writes) + CSR gather. The h
// read is one coalesced 64B txn/edge; acc atomicAdd is one 64B RMW burst/edge,
// absorbed by L2/L3 (acc ~23MB << 256MB L3). f32-atomic order nondeterminism
// is ulp-level, far under the 3.3e-2 threshold.
__global__ __launch_bounds__(256)
void k_gat_edge_scatter(const int* __restrict__ src, const int* __restrict__ dst,
                        int E, int n,
                        const float* __restrict__ ssrc, const float* __restrict__ sdst,
                        const float* __restrict__ h,
                        float* __restrict__ acc, float* __restrict__ sum) {
  long total = (long)(E + n) * 16;
  long stride = (long)gridDim.x * blockDim.x;   // multiple of 16
  for (long t = (long)blockIdx.x*blockDim.x + threadIdx.x; t < total; t += stride) {
    long g = t >> 4;
    int lane = (int)(t & 15);
    int s, d;
    if (g < E) { s = src[g]; d = dst[g]; } else { s = (int)(g - E); d = s; }
    float l = ssrc[s] + sdst[d];
    l = (l > 0.f) ? l : 0.2f*l;
    float e = expf(l);                 // no max-subtraction: ratios identical, f32-safe
    float hv = h[(size_t)s*16 + lane];
    atomicAdd(&acc[(size_t)d*16 + lane], e*hv);
    if (lane == 0) atomicAdd(&sum[d], e);
  }
}

// Node-parallel epilogue: alpha normalize + bias + relu + cluster max-pool.
__global__ void k_gat_final_pool(const float* __restrict__ acc, const float* __restrict__ sum,
                                 const float* __restrict__ bias, const int* __restrict__ cluster,
                                 float* __restrict__ pooled, int n) {
  int t = blockIdx.x*blockDim.x + threadIdx.x;
  if (t >= n*16) return;
  int g = t >> 4, lane = t & 15;
  float v = fmaf(acc[t], 1.f/sum[g], bias[lane]);
  v = fmaxf(v, 0.f);
  atomicMax((int*)(pooled + (size_t)cluster[g]*16 + lane), __float_as_int(v));
}

// ===================== final GEMV =====================
__global__ __launch_bounds__(64)
void k_gemv_out(const float* __restrict__ A, const float* __restrict__ w,
                const float* __restrict__ b, float* __restrict__ out) {
  int r = blockIdx.x, l = threadIdx.x;
  float s = 0.f;
  for (int k = l; k < 384; k += 64) s = fmaf(A[(size_t)r*384 + k], w[k], s);
#pragma unroll
  for (int o = 32; o > 0; o >>= 1) s += __shfl_down(s, o);
  if (l == 0) out[r] = s + b[0];
}

// ===================== host orchestration =====================
extern "C" void kernel_launch(void* const* d_in, const int* in_sizes, int n_in,
                              void* d_out, int out_size, void* d_ws, size_t ws_size,
                              hipStream_t stream) {
  (void)n_in; (void)out_size;
  const int B = 512, N0 = 706, C1v = 512, C2v = 400;
  const int nd  = B*40;
  const int nc0 = B*N0;
  const int nc1 = B*C1v;
  const int nc2 = B*C2v;
  const int Ed  = in_sizes[40]/2;
  const int Ec0 = in_sizes[42]/2;
  const int Ec1 = in_sizes[43]/2;

  const float* drug_x = (const float*)d_in[0];
  const float* cell_x = (const float*)d_in[1];
  const float* gW1[3] = {(const float*)d_in[2],(const float*)d_in[8],(const float*)d_in[14]};
  const float* gb1[3] = {(const float*)d_in[3],(const float*)d_in[9],(const float*)d_in[15]};
  const float* gW2[3] = {(const float*)d_in[4],(const float*)d_in[10],(const float*)d_in[16]};
  const float* gb2[3] = {(const float*)d_in[5],(const float*)d_in[11],(const float*)d_in[17]};
  const float* gg [3] = {(const float*)d_in[6],(const float*)d_in[12],(const float*)d_in[18]};
  const float* gbe[3] = {(const float*)d_in[7],(const float*)d_in[13],(const float*)d_in[19]};
  const float* demb_W = (const float*)d_in[20]; const float* demb_b = (const float*)d_in[21];
  const float* gatW[2]  = {(const float*)d_in[22],(const float*)d_in[26]};
  const float* gatAS[2] = {(const float*)d_in[23],(const float*)d_in[27]};
  const float* gatAD[2] = {(const float*)d_in[24],(const float*)d_in[28]};
  const float* gatB[2]  = {(const float*)d_in[25],(const float*)d_in[29]};
  const float* cembW1 = (const float*)d_in[30]; const float* cembb1 = (const float*)d_in[31];
  const float* cembW2 = (const float*)d_in[32]; const float* cembb2 = (const float*)d_in[33];
  const float* regW1 = (const float*)d_in[34]; const float* regb1 = (const float*)d_in[35];
  const float* regW2 = (const float*)d_in[36]; const float* regb2 = (const float*)d_in[37];
  const float* regW3 = (const float*)d_in[38]; const float* regb3 = (const float*)d_in[39];
  const int* dei = (const int*)d_in[40];
  const int* ei0 = (const int*)d_in[42];
  const int* ei1 = (const int*)d_in[43];
  const int* cl0 = (const int*)d_in[44];
  const int* cl1 = (const int*)d_in[45];
  const int *dsrc = dei,       *ddst = dei + Ed;
  const int *src0 = ei0,       *dst0 = ei0 + Ec0;
  const int *src1 = ei1,       *dst1 = ei1 + Ec1;
  float* out = (float*)d_out;

  // ---- workspace layout ----
  char* base = (char*)d_ws; size_t off = 0;
  auto AL = [&](size_t bytes)->char* { char* p = base + off; off = (off + bytes + 255) & ~(size_t)255; return p; };
  float* h_cat   = (float*)AL((size_t)512*384*4);
  float* t1      = (float*)AL((size_t)512*384*4);
  float* t2      = (float*)AL((size_t)512*384*4);
  float* xd      = (float*)AL((size_t)512*384*4);
  float* cembh   = (float*)AL((size_t)512*1024*4);
  float* pooled1 = (float*)AL((size_t)nc1*16*4);
  float* pooled2 = (float*)AL((size_t)nc2*16*4);
  float* stats   = (float*)AL(256*4);
  int*   btot    = (int*)AL(512*4);
  char*  S       = base + off;
  if (ws_size < off + (size_t)56*1024*1024) return;

  dim3 b256(256);
  auto NB = [&](long total) { return dim3((unsigned)((total + 255) / 256)); };

  // ================= DRUG BRANCH =================
  {
    size_t so = 0;
    auto SA = [&](size_t bytes)->char* { char* p = S + so; so = (so + bytes + 255) & ~(size_t)255; return p; };
    float* reps = (float*)SA((size_t)nd*384*4);
    float* xin  = (float*)SA((size_t)nd*128*4);
    float* hbuf = (float*)SA((size_t)nd*128*4);
    float* W1p  = (float*)SA((size_t)96*128*4);
    int* degD = (int*)SA((size_t)nd*4);
    int* rowD = (int*)SA(((size_t)nd+1)*4);
    int* csrD = (int*)SA((size_t)Ed*4);

    hipMemsetAsync(degD, 0, (size_t)nd*4, stream);
    k_deg<<<NB(Ed), b256, 0, stream>>>(ddst, Ed, 0, degD);
    k_scan_block<<<dim3(nd/1024), b256, 0, stream>>>(degD, nd, rowD, btot);
    k_scan_tot<<<1, 512, 0, stream>>>(btot, nd/1024);
    k_scan_add<<<NB(nd), b256, 0, stream>>>(rowD, btot, nd, Ed);
    hipMemsetAsync(degD, 0, (size_t)nd*4, stream);
    k_fill<<<NB(Ed), b256, 0, stream>>>(dsrc, ddst, Ed, 0, degD, rowD, csrD);

    k_pad<<<NB(96*128), b256, 0, stream>>>(gW1[0], 77, 128, W1p, 96, 128);

    const float* xsrc = drug_x; int xs = 77, F = 77, ds = 96;
    for (int L = 0; L < 3; ++L) {
      k_gin_gather<<<NB((long)nd*ds), b256, 0, stream>>>(rowD, csrD, xsrc, xs, F, xin, ds, nd);
      const float* W1 = (L == 0) ? W1p : gW1[L];
      int K1 = (L == 0) ? 96 : 128;
      k_gemm<1,0><<<dim3(2,320,1), b256, 0, stream>>>(xin, ds, W1, 128, gb1[L], hbuf, 128, K1);
      k_gemm<1,0><<<dim3(2,320,1), b256, 0, stream>>>(hbuf, 128, gW2[L], 128, gb2[L], xin, 128, 128);
      hipMemsetAsync(stats, 0, 256*4, stream);
      k_bn_stats<<<dim3(160), b256, 0, stream>>>(xin, nd, 128, stats);
      k_bn_apply<<<NB((long)nd*128), b256, 0, stream>>>(xin, 128, reps + L*128, 384,
                                                        stats, 1.f/nd, gg[L], gbe[L], nd*128, 128);
      xsrc = reps + L*128; xs = 384; F = 128; ds = 128;
    }
    k_drug_pool<<<dim3(512), dim3(384), 0, stream>>>(reps, xd);
    hipMemsetAsync(h_cat, 0, (size_t)512*384*4, stream);
    k_gemm<1,0><<<dim3(2,8,1), b256, 0, stream>>>(xd, 384, demb_W, 128, demb_b, h_cat, 384, 384);
  }

  // ================= CELL BRANCH (edge-parallel scatter GAT) =================
  for (int L = 0; L < 2; ++L) {
    const int n    = (L == 0) ? nc0 : nc1;
    const int E    = (L == 0) ? Ec0 : Ec1;
    const int nout = (L == 0) ? nc1 : nc2;
    const int* esrc = (L == 0) ? src0 : src1;
    const int* edst = (L == 0) ? dst0 : dst1;
    const int* clus = (L == 0) ? cl0 : cl1;
    const float* xin = (L == 0) ? cell_x : pooled1;
    const int Kin = (L == 0) ? 3 : 16;
    float* pooled = (L == 0) ? pooled1 : pooled2;

    size_t so = 0;
    auto SA = [&](size_t bytes)->char* { char* p = S + so; so = (so + bytes + 255) & ~(size_t)255; return p; };
    float* h   = (float*)SA((size_t)n*16*4);
    float* ss  = (float*)SA((size_t)n*4);
    float* sd  = (float*)SA((size_t)n*4);
    float* acc = (float*)SA((size_t)n*16*4);
    float* sum = (float*)SA((size_t)n*4);

    k_gat_node<<<NB(n), b256, 0, stream>>>(xin, Kin, gatW[L], gatAS[L], gatAD[L], h, ss, sd, n);
    hipMemsetAsync(acc, 0, (size_t)n*16*4, stream);
    hipMemsetAsync(sum, 0, (size_t)n*4, stream);
    hipMemsetAsync(pooled, 0, (size_t)nout*16*4, stream);
    k_gat_edge_scatter<<<dim3(8192), b256, 0, stream>>>(esrc, edst, E, n, ss, sd, h, acc, sum);
    k_gat_final_pool<<<NB((long)n*16), b256, 0, stream>>>(acc, sum, gatB[L], clus, pooled, n);
    hipMemsetAsync(stats, 0, 256*4, stream);
    k_bn_stats<<<dim3(256), b256, 0, stream>>>(pooled, nout, 16, stats);
    k_bn_apply<<<NB((long)nout*16), b256, 0, stream>>>(pooled, 16, pooled, 16,
                                                       stats, 1.f/nout, nullptr, nullptr, nout*16, 16);
  }

  // ================= cell embedding MLP =================
  hipMemsetAsync(cembh, 0, (size_t)512*1024*4, stream);
  k_gemm<0,1><<<dim3(16,8,8), b256, 0, stream>>>(pooled2, 6400, cembW1, 1024, nullptr, cembh, 1024, 800);
  k_bias_act<1><<<NB((long)512*1024), b256, 0, stream>>>(cembh, 1024, cembb1, 512, 1024);
  k_gemm<0,1><<<dim3(4,8,8), b256, 0, stream>>>(cembh, 1024, cembW2, 256, nullptr, h_cat + 128, 384, 128);
  k_bias_act<1><<<NB((long)512*256), b256, 0, stream>>>(h_cat + 128, 384, cembb2, 512, 256);

  // ================= regressor =================
  hipMemsetAsync(t1, 0, (size_t)512*384*4, stream);
  k_gemm<0,1><<<dim3(6,8,4), b256, 0, stream>>>(h_cat, 384, regW1, 384, nullptr, t1, 384, 96);
  k_bias_act<2><<<NB((long)512*384), b256, 0, stream>>>(t1, 384, regb1, 512, 384);
  hipMemsetAsync(t2, 0, (size_t)512*384*4, stream);
  k_gemm<0,1><<<dim3(6,8,4), b256, 0, stream>>>(t1, 384, regW2, 384, nullptr, t2, 384, 96);
  k_bias_act<2><<<NB((long)512*384), b256, 0, stream>>>(t2, 384, regb2, 512, 384);
  k_gemv_out<<<dim3(512), dim3(64), 0, stream>>>(t2, regW3, regb3, out);
}

// Round 5
// 1350.416 us; speedup vs baseline: 1.2491x; 1.2491x over previous
//
#include <hip/hip_runtime.h>
#include <math.h>

// ===================== small utility kernels =====================

__global__ void k_pad(const float* __restrict__ src, int sr, int sc,
                      float* __restrict__ dst, int dr, int dc) {
  int t = blockIdx.x*blockDim.x + threadIdx.x;
  if (t >= dr*dc) return;
  int r = t/dc, c = t - r*dc;
  dst[t] = (r < sr && c < sc) ? src[r*sc + c] : 0.f;
}

__global__ void k_deg(const int* __restrict__ dst, int E, int nsl, int* __restrict__ deg) {
  int t = blockIdx.x*blockDim.x + threadIdx.x;
  if (t >= E + nsl) return;
  int d = (t < E) ? dst[t] : (t - E);
  atomicAdd(&deg[d], 1);
}

__global__ __launch_bounds__(256)
void k_scan_block(const int* __restrict__ deg, int n, int* __restrict__ out, int* __restrict__ btot) {
  __shared__ int sh[256];
  int tid = threadIdx.x;
  int base = blockIdx.x*1024 + tid*4;
  int v0 = (base+0<n)?deg[base+0]:0;
  int v1 = (base+1<n)?deg[base+1]:0;
  int v2 = (base+2<n)?deg[base+2]:0;
  int v3 = (base+3<n)?deg[base+3]:0;
  int s = v0+v1+v2+v3;
  sh[tid] = s; __syncthreads();
  for (int o = 1; o < 256; o <<= 1) {
    int t = (tid >= o) ? sh[tid-o] : 0;
    __syncthreads();
    sh[tid] += t;
    __syncthreads();
  }
  if (tid == 255) btot[blockIdx.x] = sh[255];
  int run = sh[tid] - s;
  if (base+0<n) { out[base+0]=run; run+=v0; }
  if (base+1<n) { out[base+1]=run; run+=v1; }
  if (base+2<n) { out[base+2]=run; run+=v2; }
  if (base+3<n) { out[base+3]=run; run+=v3; }
}

__global__ __launch_bounds__(512)
void k_scan_tot(int* __restrict__ btot, int nb) {
  __shared__ int sh[512];
  int tid = threadIdx.x;
  int v = (tid < nb) ? btot[tid] : 0;
  sh[tid] = v; __syncthreads();
  for (int o = 1; o < 512; o <<= 1) {
    int t = (tid >= o) ? sh[tid-o] : 0;
    __syncthreads();
    sh[tid] += t;
    __syncthreads();
  }
  if (tid < nb) btot[tid] = sh[tid] - v;
}

__global__ void k_scan_add(int* __restrict__ rowptr, const int* __restrict__ btot, int n, int total) {
  int t = blockIdx.x*blockDim.x + threadIdx.x;
  if (t < n) rowptr[t] += btot[t >> 10];
  if (t == 0) rowptr[n] = total;
}

__global__ void k_fill(const int* __restrict__ src, const int* __restrict__ dst, int E, int nsl,
                       int* __restrict__ cursor, const int* __restrict__ rowptr, int* __restrict__ csr) {
  int t = blockIdx.x*blockDim.x + threadIdx.x;
  if (t >= E + nsl) return;
  int s, d;
  if (t < E) { s = src[t]; d = dst[t]; } else { s = t - E; d = s; }
  int slot = rowptr[d] + atomicAdd(&cursor[d], 1);
  csr[slot] = s;
}

// ===================== GIN (drug) =====================
__global__ void k_gin_gather(const int* __restrict__ rowptr, const int* __restrict__ csr,
                             const float* __restrict__ x, int xs, int F,
                             float* __restrict__ xin, int ds, int n) {
  int t = blockIdx.x*blockDim.x + threadIdx.x;
  if (t >= n*ds) return;
  int d = t/ds, f = t - d*ds;
  if (f >= F) { xin[t] = 0.f; return; }
  float acc = x[(size_t)d*xs + f];
  int e1 = rowptr[d+1];
  for (int j = rowptr[d]; j < e1; ++j) acc += x[(size_t)csr[j]*xs + f];
  xin[t] = acc;
}

__global__ __launch_bounds__(384)
void k_drug_pool(const float* __restrict__ reps, float* __restrict__ xd) {
  int b = blockIdx.x, c = threadIdx.x;
  float m = -3.0e38f;
  const float* p = reps + (size_t)b*40*384 + c;
  for (int i = 0; i < 40; ++i) m = fmaxf(m, p[(size_t)i*384]);
  xd[(size_t)b*384 + c] = m;
}

// ===================== GEMM (f32, tiled 64x64, optional split-K atomics) =====================
template<int ACT, int ATOMIC>   // ACT: 0 none, 1 relu, 2 elu (non-atomic path only)
__global__ __launch_bounds__(256)
void k_gemm(const float* __restrict__ A, int lda,
            const float* __restrict__ B, int ldb,
            const float* __restrict__ bias,
            float* __restrict__ C, int ldc, int Kchunk) {
  __shared__ __align__(16) float As[32][68];
  __shared__ __align__(16) float Bs[32][68];
  const int tid = threadIdx.x;
  const int tx = tid & 15, ty = tid >> 4;
  const int row0 = blockIdx.y << 6, col0 = blockIdx.x << 6;
  const int kb = blockIdx.z * Kchunk;
  float acc[4][4] = {{0.f}};
  for (int k0 = 0; k0 < Kchunk; k0 += 32) {
#pragma unroll
    for (int i = 0; i < 2; ++i) {
      int idx = tid + (i << 8);
      int r = idx >> 3, c = (idx & 7) << 2;
      float4 v = *(const float4*)(A + (size_t)(row0 + r)*lda + (kb + k0 + c));
      As[c+0][r]=v.x; As[c+1][r]=v.y; As[c+2][r]=v.z; As[c+3][r]=v.w;
    }
#pragma unroll
    for (int i = 0; i < 2; ++i) {
      int idx = tid + (i << 8);
      int r = idx >> 4, c = (idx & 15) << 2;
      *(float4*)&Bs[r][c] = *(const float4*)(B + (size_t)(kb + k0 + r)*ldb + (col0 + c));
    }
    __syncthreads();
#pragma unroll
    for (int kk = 0; kk < 32; ++kk) {
      float4 av = *(const float4*)&As[kk][ty << 2];
      float4 bv = *(const float4*)&Bs[kk][tx << 2];
      acc[0][0]=fmaf(av.x,bv.x,acc[0][0]); acc[0][1]=fmaf(av.x,bv.y,acc[0][1]);
      acc[0][2]=fmaf(av.x,bv.z,acc[0][2]); acc[0][3]=fmaf(av.x,bv.w,acc[0][3]);
      acc[1][0]=fmaf(av.y,bv.x,acc[1][0]); acc[1][1]=fmaf(av.y,bv.y,acc[1][1]);
      acc[1][2]=fmaf(av.y,bv.z,acc[1][2]); acc[1][3]=fmaf(av.y,bv.w,acc[1][3]);
      acc[2][0]=fmaf(av.z,bv.x,acc[2][0]); acc[2][1]=fmaf(av.z,bv.y,acc[2][1]);
      acc[2][2]=fmaf(av.z,bv.z,acc[2][2]); acc[2][3]=fmaf(av.z,bv.w,acc[2][3]);
      acc[3][0]=fmaf(av.w,bv.x,acc[3][0]); acc[3][1]=fmaf(av.w,bv.y,acc[3][1]);
      acc[3][2]=fmaf(av.w,bv.z,acc[3][2]); acc[3][3]=fmaf(av.w,bv.w,acc[3][3]);
    }
    __syncthreads();
  }
  if (ATOMIC) {
#pragma unroll
    for (int i = 0; i < 4; ++i) {
      int r = row0 + (ty<<2) + i, c = col0 + (tx<<2);
#pragma unroll
      for (int j = 0; j < 4; ++j) atomicAdd(&C[(size_t)r*ldc + c + j], acc[i][j]);
    }
  } else {
#pragma unroll
    for (int i = 0; i < 4; ++i) {
      int r = row0 + (ty<<2) + i, c = col0 + (tx<<2);
      float4 v = make_float4(acc[i][0], acc[i][1], acc[i][2], acc[i][3]);
      if (bias) { v.x += bias[c]; v.y += bias[c+1]; v.z += bias[c+2]; v.w += bias[c+3]; }
      if (ACT == 1) { v.x=fmaxf(v.x,0.f); v.y=fmaxf(v.y,0.f); v.z=fmaxf(v.z,0.f); v.w=fmaxf(v.w,0.f); }
      else if (ACT == 2) {
        v.x = v.x>0.f?v.x:expm1f(v.x); v.y = v.y>0.f?v.y:expm1f(v.y);
        v.z = v.z>0.f?v.z:expm1f(v.z); v.w = v.w>0.f?v.w:expm1f(v.w);
      }
      *(float4*)(C + (size_t)r*ldc + c) = v;
    }
  }
}

template<int ACT>
__global__ void k_bias_act(float* __restrict__ C, int ldc, const float* __restrict__ bias, int M, int N) {
  int t = blockIdx.x*blockDim.x + threadIdx.x;
  if (t >= M*N) return;
  int r = t / N, c = t - r*N;
  float v = C[(size_t)r*ldc + c] + bias[c];
  if (ACT == 1) v = fmaxf(v, 0.f);
  else if (ACT == 2) v = v > 0.f ? v : expm1f(v);
  C[(size_t)r*ldc + c] = v;
}

// ===================== BatchNorm =====================
__global__ __launch_bounds__(256)
void k_bn_stats(const float* __restrict__ x, int rows, int cols, float* __restrict__ acc) {
  __shared__ float sh[256], sh2[256];
  int tid = threadIdx.x;
  int nth = gridDim.x * 256;
  int t = blockIdx.x*256 + tid;
  int c = t % cols;
  int r0 = t / cols;
  int rstep = nth / cols;
  float s = 0.f, s2 = 0.f;
  for (int r = r0; r < rows; r += rstep) {
    float v = x[(size_t)r*cols + c];
    s += v; s2 = fmaf(v, v, s2);
  }
  sh[tid] = s; sh2[tid] = s2; __syncthreads();
  for (int o = 128; o >= cols; o >>= 1) {
    if (tid < o) { sh[tid] += sh[tid+o]; sh2[tid] += sh2[tid+o]; }
    __syncthreads();
  }
  if (tid < cols) { atomicAdd(&acc[tid], sh[tid]); atomicAdd(&acc[cols+tid], sh2[tid]); }
}

__global__ void k_bn_apply(const float* __restrict__ x, int xs,
                           float* __restrict__ y, int ys,
                           const float* __restrict__ acc, float invn,
                           const float* __restrict__ g, const float* __restrict__ be,
                           int total, int cols) {
  int t = blockIdx.x*blockDim.x + threadIdx.x;
  if (t >= total) return;
  int c = t % cols;
  int r = t / cols;
  float mu = acc[c] * invn;
  float var = fmaxf(acc[cols+c]*invn - mu*mu, 0.f);
  float rstd = rsqrtf(var + 1e-5f);
  float v = (x[(size_t)r*xs + c] - mu) * rstd;
  if (g) v = fmaf(v, g[c], be[c]);
  y[(size_t)r*ys + c] = v;
}

// ===================== fused per-batch GAT layer =====================
// The cell graphs are block-diagonal: batch b's nodes are [b*NODES,(b+1)*NODES),
// its edges are contiguous (layer0: fixed [b*Eb,(b+1)*Eb); layer1: src-sorted,
// range found by binary search), and clusters map into [b*NPOOL,(b+1)*NPOOL).
// One workgroup per batch item does: h = x@W, ssrc/sdst, edge-parallel softmax
// aggregation via LDS atomics (16 lanes/edge), normalize+bias+relu, cluster
// max-pool in LDS (h storage reused), single coalesced 32KB block write.
// No global atomics, no CSR.
template<int NODES, int NPOOL, int KIN, int SORTED>
__global__ __launch_bounds__(512)
void k_gat_fused(const float* __restrict__ x,
                 const int* __restrict__ esrc, const int* __restrict__ edst, int Eb,
                 const float* __restrict__ W, const float* __restrict__ as_,
                 const float* __restrict__ ad_, const float* __restrict__ bias,
                 const int* __restrict__ cluster,
                 float* __restrict__ pooled) {
  __shared__ float sh[NODES*16];     // h; reused as pool buffer at the end
  __shared__ float sacc[NODES*16];
  __shared__ float sss[NODES], ssd[NODES], ssum[NODES];
  __shared__ float sW[KIN*16];
  __shared__ int sr[2];
  const int b = blockIdx.x;
  const int tid = threadIdx.x;
  const int nbase = b*NODES;

  if (tid < KIN*16) sW[tid] = W[tid];
  if (SORTED && tid == 0) {          // edge range for this block in sorted src
    int a = 0, c = Eb;
    while (a < c) { int m = (a+c) >> 1; if (esrc[m] < nbase) a = m+1; else c = m; }
    sr[0] = a;
    c = Eb;
    int nend = nbase + NODES;
    while (a < c) { int m = (a+c) >> 1; if (esrc[m] < nend) a = m+1; else c = m; }
    sr[1] = a;
  }
  for (int i = tid; i < NODES*16; i += 512) sacc[i] = 0.f;
  for (int i = tid; i < NODES; i += 512) ssum[i] = 0.f;
  __syncthreads();

  // h = x @ W  (KIN -> 16), per (node, feature)
  for (int i = tid; i < NODES*16; i += 512) {
    int n = i >> 4, f = i & 15;
    const float* xp = x + (size_t)(nbase + n)*KIN;
    float hv = 0.f;
#pragma unroll
    for (int j = 0; j < KIN; ++j) hv = fmaf(xp[j], sW[j*16 + f], hv);
    sh[i] = hv;
  }
  __syncthreads();

  for (int n = tid; n < NODES; n += 512) {
    float s1 = 0.f, s2 = 0.f;
#pragma unroll
    for (int f = 0; f < 16; ++f) {
      float hv = sh[n*16 + f];
      s1 = fmaf(hv, as_[f], s1); s2 = fmaf(hv, ad_[f], s2);
    }
    sss[n] = s1; ssd[n] = s2;
  }
  __syncthreads();

  int e0, e1;
  if (SORTED) { e0 = sr[0]; e1 = sr[1]; } else { e0 = b*Eb; e1 = e0 + Eb; }
  const int Eblk = e1 - e0;
  const int total = Eblk + NODES;    // + self-loops
  const int lane = tid & 15, grp = tid >> 4;   // 32 edge groups
  for (int e = grp; e < total; e += 32) {
    int s, d;
    if (e < Eblk) { s = esrc[e0+e] - nbase; d = edst[e0+e] - nbase; }
    else { s = e - Eblk; d = s; }
    float l = sss[s] + ssd[d];
    l = (l > 0.f) ? l : 0.2f*l;
    float ex = __expf(l);            // no max-subtraction: ratios identical, f32-safe
    atomicAdd(&sacc[d*16 + lane], ex * sh[s*16 + lane]);
    if (lane == 0) atomicAdd(&ssum[d], ex);
  }
  __syncthreads();

  // reuse sh as the pool buffer (relu output >= 0, so init 0 is the identity)
  for (int i = tid; i < NPOOL*16; i += 512) sh[i] = 0.f;
  __syncthreads();
  for (int i = tid; i < NODES*16; i += 512) {
    int n = i >> 4, f = i & 15;
    float v = fmaf(sacc[i], 1.f/ssum[n], bias[f]);
    v = fmaxf(v, 0.f);
    int c = cluster[nbase + n] - b*NPOOL;
    atomicMax((int*)&sh[c*16 + f], __float_as_int(v));
  }
  __syncthreads();
  for (int i = tid; i < NPOOL*16; i += 512)
    pooled[(size_t)b*NPOOL*16 + i] = sh[i];
}

// ===================== final GEMV =====================
__global__ __launch_bounds__(64)
void k_gemv_out(const float* __restrict__ A, const float* __restrict__ w,
                const float* __restrict__ b, float* __restrict__ out) {
  int r = blockIdx.x, l = threadIdx.x;
  float s = 0.f;
  for (int k = l; k < 384; k += 64) s = fmaf(A[(size_t)r*384 + k], w[k], s);
#pragma unroll
  for (int o = 32; o > 0; o >>= 1) s += __shfl_down(s, o);
  if (l == 0) out[r] = s + b[0];
}

// ===================== host orchestration =====================
extern "C" void kernel_launch(void* const* d_in, const int* in_sizes, int n_in,
                              void* d_out, int out_size, void* d_ws, size_t ws_size,
                              hipStream_t stream) {
  (void)n_in; (void)out_size;
  const int B = 512, N0 = 706, C1v = 512, C2v = 400;
  const int nd  = B*40;
  const int nc1 = B*C1v;
  const int nc2 = B*C2v;
  const int Ed  = in_sizes[40]/2;
  const int Ec0 = in_sizes[42]/2;
  const int Ec1 = in_sizes[43]/2;

  const float* drug_x = (const float*)d_in[0];
  const float* cell_x = (const float*)d_in[1];
  const float* gW1[3] = {(const float*)d_in[2],(const float*)d_in[8],(const float*)d_in[14]};
  const float* gb1[3] = {(const float*)d_in[3],(const float*)d_in[9],(const float*)d_in[15]};
  const float* gW2[3] = {(const float*)d_in[4],(const float*)d_in[10],(const float*)d_in[16]};
  const float* gb2[3] = {(const float*)d_in[5],(const float*)d_in[11],(const float*)d_in[17]};
  const float* gg [3] = {(const float*)d_in[6],(const float*)d_in[12],(const float*)d_in[18]};
  const float* gbe[3] = {(const float*)d_in[7],(const float*)d_in[13],(const float*)d_in[19]};
  const float* demb_W = (const float*)d_in[20]; const float* demb_b = (const float*)d_in[21];
  const float* gatW[2]  = {(const float*)d_in[22],(const float*)d_in[26]};
  const float* gatAS[2] = {(const float*)d_in[23],(const float*)d_in[27]};
  const float* gatAD[2] = {(const float*)d_in[24],(const float*)d_in[28]};
  const float* gatB[2]  = {(const float*)d_in[25],(const float*)d_in[29]};
  const float* cembW1 = (const float*)d_in[30]; const float* cembb1 = (const float*)d_in[31];
  const float* cembW2 = (const float*)d_in[32]; const float* cembb2 = (const float*)d_in[33];
  const float* regW1 = (const float*)d_in[34]; const float* regb1 = (const float*)d_in[35];
  const float* regW2 = (const float*)d_in[36]; const float* regb2 = (const float*)d_in[37];
  const float* regW3 = (const float*)d_in[38]; const float* regb3 = (const float*)d_in[39];
  const int* dei = (const int*)d_in[40];
  const int* ei0 = (const int*)d_in[42];
  const int* ei1 = (const int*)d_in[43];
  const int* cl0 = (const int*)d_in[44];
  const int* cl1 = (const int*)d_in[45];
  const int *dsrc = dei,       *ddst = dei + Ed;
  const int *src0 = ei0,       *dst0 = ei0 + Ec0;
  const int *src1 = ei1,       *dst1 = ei1 + Ec1;
  float* out = (float*)d_out;

  // ---- workspace layout ----
  char* base = (char*)d_ws; size_t off = 0;
  auto AL = [&](size_t bytes)->char* { char* p = base + off; off = (off + bytes + 255) & ~(size_t)255; return p; };
  float* h_cat   = (float*)AL((size_t)512*384*4);
  float* t1      = (float*)AL((size_t)512*384*4);
  float* t2      = (float*)AL((size_t)512*384*4);
  float* xd      = (float*)AL((size_t)512*384*4);
  float* cembh   = (float*)AL((size_t)512*1024*4);
  float* pooled1 = (float*)AL((size_t)nc1*16*4);
  float* pooled2 = (float*)AL((size_t)nc2*16*4);
  float* stats   = (float*)AL(256*4);
  int*   btot    = (int*)AL(512*4);
  char*  S       = base + off;
  if (ws_size < off + (size_t)56*1024*1024) return;

  dim3 b256(256);
  auto NB = [&](long total) { return dim3((unsigned)((total + 255) / 256)); };

  // ================= DRUG BRANCH =================
  {
    size_t so = 0;
    auto SA = [&](size_t bytes)->char* { char* p = S + so; so = (so + bytes + 255) & ~(size_t)255; return p; };
    float* reps = (float*)SA((size_t)nd*384*4);
    float* xin  = (float*)SA((size_t)nd*128*4);
    float* hbuf = (float*)SA((size_t)nd*128*4);
    float* W1p  = (float*)SA((size_t)96*128*4);
    int* degD = (int*)SA((size_t)nd*4);
    int* rowD = (int*)SA(((size_t)nd+1)*4);
    int* csrD = (int*)SA((size_t)Ed*4);

    hipMemsetAsync(degD, 0, (size_t)nd*4, stream);
    k_deg<<<NB(Ed), b256, 0, stream>>>(ddst, Ed, 0, degD);
    k_scan_block<<<dim3(nd/1024), b256, 0, stream>>>(degD, nd, rowD, btot);
    k_scan_tot<<<1, 512, 0, stream>>>(btot, nd/1024);
    k_scan_add<<<NB(nd), b256, 0, stream>>>(rowD, btot, nd, Ed);
    hipMemsetAsync(degD, 0, (size_t)nd*4, stream);
    k_fill<<<NB(Ed), b256, 0, stream>>>(dsrc, ddst, Ed, 0, degD, rowD, csrD);

    k_pad<<<NB(96*128), b256, 0, stream>>>(gW1[0], 77, 128, W1p, 96, 128);

    const float* xsrc = drug_x; int xs = 77, F = 77, ds = 96;
    for (int L = 0; L < 3; ++L) {
      k_gin_gather<<<NB((long)nd*ds), b256, 0, stream>>>(rowD, csrD, xsrc, xs, F, xin, ds, nd);
      const float* W1 = (L == 0) ? W1p : gW1[L];
      int K1 = (L == 0) ? 96 : 128;
      k_gemm<1,0><<<dim3(2,320,1), b256, 0, stream>>>(xin, ds, W1, 128, gb1[L], hbuf, 128, K1);
      k_gemm<1,0><<<dim3(2,320,1), b256, 0, stream>>>(hbuf, 128, gW2[L], 128, gb2[L], xin, 128, 128);
      hipMemsetAsync(stats, 0, 256*4, stream);
      k_bn_stats<<<dim3(160), b256, 0, stream>>>(xin, nd, 128, stats);
      k_bn_apply<<<NB((long)nd*128), b256, 0, stream>>>(xin, 128, reps + L*128, 384,
                                                        stats, 1.f/nd, gg[L], gbe[L], nd*128, 128);
      xsrc = reps + L*128; xs = 384; F = 128; ds = 128;
    }
    k_drug_pool<<<dim3(512), dim3(384), 0, stream>>>(reps, xd);
    hipMemsetAsync(h_cat, 0, (size_t)512*384*4, stream);
    k_gemm<1,0><<<dim3(2,8,1), b256, 0, stream>>>(xd, 384, demb_W, 128, demb_b, h_cat, 384, 384);
  }

  // ================= CELL BRANCH: two fused per-batch GAT layers =================
  k_gat_fused<706,512,3,0><<<dim3(512), dim3(512), 0, stream>>>(
      cell_x, src0, dst0, Ec0/512, gatW[0], gatAS[0], gatAD[0], gatB[0], cl0, pooled1);
  hipMemsetAsync(stats, 0, 256*4, stream);
  k_bn_stats<<<dim3(256), b256, 0, stream>>>(pooled1, nc1, 16, stats);
  k_bn_apply<<<NB((long)nc1*16), b256, 0, stream>>>(pooled1, 16, pooled1, 16,
                                                    stats, 1.f/nc1, nullptr, nullptr, nc1*16, 16);

  k_gat_fused<512,400,16,1><<<dim3(512), dim3(512), 0, stream>>>(
      pooled1, src1, dst1, Ec1, gatW[1], gatAS[1], gatAD[1], gatB[1], cl1, pooled2);
  hipMemsetAsync(stats, 0, 256*4, stream);
  k_bn_stats<<<dim3(256), b256, 0, stream>>>(pooled2, nc2, 16, stats);
  k_bn_apply<<<NB((long)nc2*16), b256, 0, stream>>>(pooled2, 16, pooled2, 16,
                                                    stats, 1.f/nc2, nullptr, nullptr, nc2*16, 16);

  // ================= cell embedding MLP =================
  hipMemsetAsync(cembh, 0, (size_t)512*1024*4, stream);
  k_gemm<0,1><<<dim3(16,8,8), b256, 0, stream>>>(pooled2, 6400, cembW1, 1024, nullptr, cembh, 1024, 800);
  k_bias_act<1><<<NB((long)512*1024), b256, 0, stream>>>(cembh, 1024, cembb1, 512, 1024);
  k_gemm<0,1><<<dim3(4,8,8), b256, 0, stream>>>(cembh, 1024, cembW2, 256, nullptr, h_cat + 128, 384, 128);
  k_bias_act<1><<<NB((long)512*256), b256, 0, stream>>>(h_cat + 128, 384, cembb2, 512, 256);

  // ================= regressor =================
  hipMemsetAsync(t1, 0, (size_t)512*384*4, stream);
  k_gemm<0,1><<<dim3(6,8,4), b256, 0, stream>>>(h_cat, 384, regW1, 384, nullptr, t1, 384, 96);
  k_bias_act<2><<<NB((long)512*384), b256, 0, stream>>>(t1, 384, regb1, 512, 384);
  hipMemsetAsync(t2, 0, (size_t)512*384*4, stream);
  k_gemm<0,1><<<dim3(6,8,4), b256, 0, stream>>>(t1, 384, regW2, 384, nullptr, t2, 384, 96);
  k_bias_act<2><<<NB((long)512*384), b256, 0, stream>>>(t2, 384, regb2, 512, 384);
  k_gemv_out<<<dim3(512), dim3(64), 0, stream>>>(t2, regW3, regb3, out);
}

// Round 6
// 905.299 us; speedup vs baseline: 1.8633x; 1.4917x over previous
//
#include <hip/hip_runtime.h>
#include <math.h>

// ===================== small utility kernels =====================

__global__ void k_pad(const float* __restrict__ src, int sr, int sc,
                      float* __restrict__ dst, int dr, int dc) {
  int t = blockIdx.x*blockDim.x + threadIdx.x;
  if (t >= dr*dc) return;
  int r = t/dc, c = t - r*dc;
  dst[t] = (r < sr && c < sc) ? src[r*sc + c] : 0.f;
}

__global__ void k_deg(const int* __restrict__ dst, int E, int nsl, int* __restrict__ deg) {
  int t = blockIdx.x*blockDim.x + threadIdx.x;
  if (t >= E + nsl) return;
  int d = (t < E) ? dst[t] : (t - E);
  atomicAdd(&deg[d], 1);
}

__global__ __launch_bounds__(256)
void k_scan_block(const int* __restrict__ deg, int n, int* __restrict__ out, int* __restrict__ btot) {
  __shared__ int sh[256];
  int tid = threadIdx.x;
  int base = blockIdx.x*1024 + tid*4;
  int v0 = (base+0<n)?deg[base+0]:0;
  int v1 = (base+1<n)?deg[base+1]:0;
  int v2 = (base+2<n)?deg[base+2]:0;
  int v3 = (base+3<n)?deg[base+3]:0;
  int s = v0+v1+v2+v3;
  sh[tid] = s; __syncthreads();
  for (int o = 1; o < 256; o <<= 1) {
    int t = (tid >= o) ? sh[tid-o] : 0;
    __syncthreads();
    sh[tid] += t;
    __syncthreads();
  }
  if (tid == 255) btot[blockIdx.x] = sh[255];
  int run = sh[tid] - s;
  if (base+0<n) { out[base+0]=run; run+=v0; }
  if (base+1<n) { out[base+1]=run; run+=v1; }
  if (base+2<n) { out[base+2]=run; run+=v2; }
  if (base+3<n) { out[base+3]=run; run+=v3; }
}

__global__ __launch_bounds__(512)
void k_scan_tot(int* __restrict__ btot, int nb) {
  __shared__ int sh[512];
  int tid = threadIdx.x;
  int v = (tid < nb) ? btot[tid] : 0;
  sh[tid] = v; __syncthreads();
  for (int o = 1; o < 512; o <<= 1) {
    int t = (tid >= o) ? sh[tid-o] : 0;
    __syncthreads();
    sh[tid] += t;
    __syncthreads();
  }
  if (tid < nb) btot[tid] = sh[tid] - v;
}

__global__ void k_scan_add(int* __restrict__ rowptr, const int* __restrict__ btot, int n, int total) {
  int t = blockIdx.x*blockDim.x + threadIdx.x;
  if (t < n) rowptr[t] += btot[t >> 10];
  if (t == 0) rowptr[n] = total;
}

__global__ void k_fill(const int* __restrict__ src, const int* __restrict__ dst, int E, int nsl,
                       int* __restrict__ cursor, const int* __restrict__ rowptr, int* __restrict__ csr) {
  int t = blockIdx.x*blockDim.x + threadIdx.x;
  if (t >= E + nsl) return;
  int s, d;
  if (t < E) { s = src[t]; d = dst[t]; } else { s = t - E; d = s; }
  int slot = rowptr[d] + atomicAdd(&cursor[d], 1);
  csr[slot] = s;
}

// ===================== GIN (drug) =====================
__global__ void k_gin_gather(const int* __restrict__ rowptr, const int* __restrict__ csr,
                             const float* __restrict__ x, int xs, int F,
                             float* __restrict__ xin, int ds, int n) {
  int t = blockIdx.x*blockDim.x + threadIdx.x;
  if (t >= n*ds) return;
  int d = t/ds, f = t - d*ds;
  if (f >= F) { xin[t] = 0.f; return; }
  float acc = x[(size_t)d*xs + f];
  int e1 = rowptr[d+1];
  for (int j = rowptr[d]; j < e1; ++j) acc += x[(size_t)csr[j]*xs + f];
  xin[t] = acc;
}

__global__ __launch_bounds__(384)
void k_drug_pool(const float* __restrict__ reps, float* __restrict__ xd) {
  int b = blockIdx.x, c = threadIdx.x;
  float m = -3.0e38f;
  const float* p = reps + (size_t)b*40*384 + c;
  for (int i = 0; i < 40; ++i) m = fmaxf(m, p[(size_t)i*384]);
  xd[(size_t)b*384 + c] = m;
}

// ===================== GEMM (f32, tiled 64x64; PART=split-K partial store) ==========
// No float atomics anywhere (global f32 atomicAdd is a CAS loop on gfx950).
template<int ACT, int PART>   // ACT: 0 none, 1 relu, 2 elu (non-partial path only)
__global__ __launch_bounds__(256)
void k_gemm(const float* __restrict__ A, int lda,
            const float* __restrict__ B, int ldb,
            const float* __restrict__ bias,
            float* __restrict__ C, int ldc, int Kchunk, long pstride) {
  __shared__ __align__(16) float As[32][68];
  __shared__ __align__(16) float Bs[32][68];
  const int tid = threadIdx.x;
  const int tx = tid & 15, ty = tid >> 4;
  const int row0 = blockIdx.y << 6, col0 = blockIdx.x << 6;
  const int kb = blockIdx.z * Kchunk;
  if (PART) C += (size_t)blockIdx.z * pstride;
  float acc[4][4] = {{0.f}};
  for (int k0 = 0; k0 < Kchunk; k0 += 32) {
#pragma unroll
    for (int i = 0; i < 2; ++i) {
      int idx = tid + (i << 8);
      int r = idx >> 3, c = (idx & 7) << 2;
      float4 v = *(const float4*)(A + (size_t)(row0 + r)*lda + (kb + k0 + c));
      As[c+0][r]=v.x; As[c+1][r]=v.y; As[c+2][r]=v.z; As[c+3][r]=v.w;
    }
#pragma unroll
    for (int i = 0; i < 2; ++i) {
      int idx = tid + (i << 8);
      int r = idx >> 4, c = (idx & 15) << 2;
      *(float4*)&Bs[r][c] = *(const float4*)(B + (size_t)(kb + k0 + r)*ldb + (col0 + c));
    }
    __syncthreads();
#pragma unroll
    for (int kk = 0; kk < 32; ++kk) {
      float4 av = *(const float4*)&As[kk][ty << 2];
      float4 bv = *(const float4*)&Bs[kk][tx << 2];
      acc[0][0]=fmaf(av.x,bv.x,acc[0][0]); acc[0][1]=fmaf(av.x,bv.y,acc[0][1]);
      acc[0][2]=fmaf(av.x,bv.z,acc[0][2]); acc[0][3]=fmaf(av.x,bv.w,acc[0][3]);
      acc[1][0]=fmaf(av.y,bv.x,acc[1][0]); acc[1][1]=fmaf(av.y,bv.y,acc[1][1]);
      acc[1][2]=fmaf(av.y,bv.z,acc[1][2]); acc[1][3]=fmaf(av.y,bv.w,acc[1][3]);
      acc[2][0]=fmaf(av.z,bv.x,acc[2][0]); acc[2][1]=fmaf(av.z,bv.y,acc[2][1]);
      acc[2][2]=fmaf(av.z,bv.z,acc[2][2]); acc[2][3]=fmaf(av.z,bv.w,acc[2][3]);
      acc[3][0]=fmaf(av.w,bv.x,acc[3][0]); acc[3][1]=fmaf(av.w,bv.y,acc[3][1]);
      acc[3][2]=fmaf(av.w,bv.z,acc[3][2]); acc[3][3]=fmaf(av.w,bv.w,acc[3][3]);
    }
    __syncthreads();
  }
#pragma unroll
  for (int i = 0; i < 4; ++i) {
    int r = row0 + (ty<<2) + i, c = col0 + (tx<<2);
    float4 v = make_float4(acc[i][0], acc[i][1], acc[i][2], acc[i][3]);
    if (!PART) {
      if (bias) { v.x += bias[c]; v.y += bias[c+1]; v.z += bias[c+2]; v.w += bias[c+3]; }
      if (ACT == 1) { v.x=fmaxf(v.x,0.f); v.y=fmaxf(v.y,0.f); v.z=fmaxf(v.z,0.f); v.w=fmaxf(v.w,0.f); }
      else if (ACT == 2) {
        v.x = v.x>0.f?v.x:expm1f(v.x); v.y = v.y>0.f?v.y:expm1f(v.y);
        v.z = v.z>0.f?v.z:expm1f(v.z); v.w = v.w>0.f?v.w:expm1f(v.w);
      }
    }
    *(float4*)(C + (size_t)r*ldc + c) = v;
  }
}

// sum split-K partials + bias + activation
template<int ACT>
__global__ void k_reduce(const float* __restrict__ parts, int np, long pstride,
                         const float* __restrict__ bias,
                         float* __restrict__ out, int ldo, int M, int N) {
  int t = blockIdx.x*blockDim.x + threadIdx.x;
  if (t >= M*N) return;
  int r = t / N, c = t - r*N;
  float s = 0.f;
  for (int z = 0; z < np; ++z) s += parts[(size_t)z*pstride + t];
  s += bias[c];
  if (ACT == 1) s = fmaxf(s, 0.f);
  else if (ACT == 2) s = s > 0.f ? s : expm1f(s);
  out[(size_t)r*ldo + c] = s;
}

// ===================== BatchNorm (no float atomics) =====================
__global__ __launch_bounds__(256)
void k_bn_stats_p(const float* __restrict__ x, int rows, int C, float* __restrict__ parts) {
  __shared__ float sh[256], sh2[256];
  int tid = threadIdx.x;
  int c = tid % C;
  int rpb = 256 / C;
  int r0 = blockIdx.x*rpb + tid / C;
  int rstep = gridDim.x * rpb;
  float s = 0.f, s2 = 0.f;
  for (int r = r0; r < rows; r += rstep) {
    float v = x[(size_t)r*C + c];
    s += v; s2 = fmaf(v, v, s2);
  }
  sh[tid] = s; sh2[tid] = s2; __syncthreads();
  for (int o = 128; o >= C; o >>= 1) {
    if (tid < o) { sh[tid] += sh[tid+o]; sh2[tid] += sh2[tid+o]; }
    __syncthreads();
  }
  if (tid < C) { parts[blockIdx.x*2*C + tid] = sh[tid]; parts[blockIdx.x*2*C + C + tid] = sh2[tid]; }
}

__global__ void k_bn_fin(const float* __restrict__ parts, int nb, int C, float invn,
                         float* __restrict__ stats) {
  int t = threadIdx.x;
  if (t >= C) return;
  float s = 0.f, s2 = 0.f;
  for (int z = 0; z < nb; ++z) { s += parts[z*2*C + t]; s2 += parts[z*2*C + C + t]; }
  float mu = s * invn;
  float var = fmaxf(s2*invn - mu*mu, 0.f);
  stats[t] = mu;
  stats[C + t] = rsqrtf(var + 1e-5f);
}

__global__ void k_bn_apply(const float* __restrict__ x, int xs,
                           float* __restrict__ y, int ys,
                           const float* __restrict__ stats,
                           const float* __restrict__ g, const float* __restrict__ be,
                           int total, int C) {
  int t = blockIdx.x*blockDim.x + threadIdx.x;
  if (t >= total) return;
  int c = t % C;
  int r = t / C;
  float v = (x[(size_t)r*xs + c] - stats[c]) * stats[C + c];
  if (g) v = fmaf(v, g[c], be[c]);
  y[(size_t)r*ys + c] = v;
}

// ===================== fused per-batch GAT layer (atomic-free floats) ============
// Block-diagonal graphs: one workgroup per batch item, everything in LDS.
// Counting-sort edges by dst (int LDS atomics only: native ds_add), storing
// (src:u16, exp:f32) per slot; exp computed ONCE per edge. Gather phase is
// atomic-free: 16 lanes/node accumulate in registers from LDS. Pool via int
// atomicMax (native; values >= 0). srow doubles as the scatter cursor.
template<int NODES, int NPOOL, int KIN, int MAXE, int SORTED>
__global__ __launch_bounds__(512)
void k_gat_lds(const float* __restrict__ x,
               const int* __restrict__ esrc, const int* __restrict__ edst, int Earg,
               const float* __restrict__ W, const float* __restrict__ as_,
               const float* __restrict__ ad_, const float* __restrict__ bias,
               const int* __restrict__ cluster,
               float* __restrict__ pooled) {
  __shared__ float sh[NODES*16];
  __shared__ float sew[MAXE];
  __shared__ unsigned short scsr[MAXE];
  __shared__ float sss[NODES], ssd[NODES];
  __shared__ int srow[NODES+1];
  __shared__ float spool[NPOOL*16];
  __shared__ float sWl[KIN*16 + 16];
  __shared__ float sas[16], sad[16];
  __shared__ int schunk[32];
  __shared__ int sr2[2];
  const int b = blockIdx.x;
  const int tid = threadIdx.x;
  const int nbase = b*NODES;

  if (tid < KIN*16) sWl[tid] = W[tid];
  if (tid >= 64 && tid < 80)  sWl[KIN*16 + tid-64] = bias[tid-64];
  if (tid >= 80 && tid < 96)  sas[tid-80] = as_[tid-80];
  if (tid >= 96 && tid < 112) sad[tid-96] = ad_[tid-96];
  if (SORTED && tid == 0) {
    int a = 0, c = Earg;
    while (a < c) { int m = (a+c) >> 1; if (esrc[m] < nbase) a = m+1; else c = m; }
    sr2[0] = a;
    c = Earg;
    int nend = nbase + NODES;
    while (a < c) { int m = (a+c) >> 1; if (esrc[m] < nend) a = m+1; else c = m; }
    sr2[1] = a;
  }
  for (int i = tid; i <= NODES; i += 512) srow[i] = 0;
  for (int i = tid; i < NPOOL*16; i += 512) spool[i] = 0.f;
  __syncthreads();

  int e0, Eblk;
  if (SORTED) { e0 = sr2[0]; Eblk = sr2[1] - sr2[0]; }
  else        { e0 = b*Earg; Eblk = Earg; }

  // (a) degree count (int LDS atomics, native)
  for (int e = tid; e < Eblk; e += 512) atomicAdd(&srow[(edst[e0+e] - nbase) + 1], 1);
  // (b) h = x@W with lane-shuffle x broadcast; fold in ssrc/sdst via 16-lane reduce
  for (int i = tid; i < NODES*16; i += 512) {
    int n = i >> 4, f = i & 15;
    const float* xp = x + (size_t)(nbase + n)*KIN;
    float xq = (f < KIN) ? xp[f] : 0.f;
    float hv = 0.f;
#pragma unroll
    for (int j = 0; j < KIN; ++j) hv = fmaf(__shfl(xq, j, 16), sWl[j*16 + f], hv);
    sh[i] = hv;
    float s1 = hv * sas[f], s2 = hv * sad[f];
#pragma unroll
    for (int m = 8; m >= 1; m >>= 1) { s1 += __shfl_xor(s1, m); s2 += __shfl_xor(s2, m); }
    if (f == 0) { sss[n] = s1; ssd[n] = s2; }
  }
  __syncthreads();

  // (c) chunked prefix scan: srow[n] = start offset of node n
  constexpr int NC = 32, CS = (NODES + NC - 1) / NC;
  if (tid < NC) {
    int run = 0, lo = tid*CS, hi = (tid+1)*CS < NODES ? (tid+1)*CS : NODES;
    for (int i = lo; i < hi; ++i) { run += srow[i+1]; srow[i+1] = run; }
    schunk[tid] = run;
  }
  __syncthreads();
  if (tid == 0) { int base = 0; for (int c = 0; c < NC; ++c) { int t2 = schunk[c]; schunk[c] = base; base += t2; } }
  __syncthreads();
  for (int i = tid; i < NODES; i += 512) srow[i+1] += schunk[i/CS];
  __syncthreads();

  // (d) scatter (src,exp) into CSR slots; srow[d] is the live cursor
  for (int e = tid; e < Eblk; e += 512) {
    int s = esrc[e0+e] - nbase, d = edst[e0+e] - nbase;
    float l = sss[s] + ssd[d];
    l = (l > 0.f) ? l : 0.2f*l;
    float ex = __expf(l);              // no max-subtraction: ratios identical, f32-safe
    int slot = atomicAdd(&srow[d], 1);
    scsr[slot] = (unsigned short)s;
    sew[slot] = ex;
  }
  __syncthreads();
  // post-scatter: srow[n] = end(n) = start(n+1); start(0) = 0

  // (e) gather: 16 lanes per node, register accumulation, zero atomics
  {
    const int lane = tid & 15, grp = tid >> 4;
    for (int n = grp; n < NODES; n += 32) {
      float ls = sss[n] + ssd[n];
      ls = (ls > 0.f) ? ls : 0.2f*ls;
      float exs = __expf(ls);                        // self-loop
      float accv = exs * sh[n*16 + lane], sum = exs;
      int j0 = (n > 0) ? srow[n-1] : 0, j1 = srow[n];
      for (int j = j0; j < j1; ++j) {
        int s = scsr[j];
        float e = sew[j];
        accv = fmaf(e, sh[s*16 + lane], accv);
        sum += e;
      }
      float v = fmaf(accv, 1.f/sum, sWl[KIN*16 + lane]);
      v = fmaxf(v, 0.f);
      int c = cluster[nbase + n] - b*NPOOL;
      atomicMax((int*)&spool[c*16 + lane], __float_as_int(v));
    }
  }
  __syncthreads();
  float* po = pooled + (size_t)b*NPOOL*16;
  for (int i = tid; i < NPOOL*16; i += 512) po[i] = spool[i];
}

// ===================== final GEMV =====================
__global__ __launch_bounds__(64)
void k_gemv_out(const float* __restrict__ A, const float* __restrict__ w,
                const float* __restrict__ b, float* __restrict__ out) {
  int r = blockIdx.x, l = threadIdx.x;
  float s = 0.f;
  for (int k = l; k < 384; k += 64) s = fmaf(A[(size_t)r*384 + k], w[k], s);
#pragma unroll
  for (int o = 32; o > 0; o >>= 1) s += __shfl_down(s, o);
  if (l == 0) out[r] = s + b[0];
}

// ===================== host orchestration =====================
extern "C" void kernel_launch(void* const* d_in, const int* in_sizes, int n_in,
                              void* d_out, int out_size, void* d_ws, size_t ws_size,
                              hipStream_t stream) {
  (void)n_in; (void)out_size;
  const int B = 512;
  const int nd  = B*40;
  const int nc1 = B*512;
  const int nc2 = B*400;
  const int Ed  = in_sizes[40]/2;
  const int Ec0 = in_sizes[42]/2;
  const int Ec1 = in_sizes[43]/2;

  const float* drug_x = (const float*)d_in[0];
  const float* cell_x = (const float*)d_in[1];
  const float* gW1[3] = {(const float*)d_in[2],(const float*)d_in[8],(const float*)d_in[14]};
  const float* gb1[3] = {(const float*)d_in[3],(const float*)d_in[9],(const float*)d_in[15]};
  const float* gW2[3] = {(const float*)d_in[4],(const float*)d_in[10],(const float*)d_in[16]};
  const float* gb2[3] = {(const float*)d_in[5],(const float*)d_in[11],(const float*)d_in[17]};
  const float* gg [3] = {(const float*)d_in[6],(const float*)d_in[12],(const float*)d_in[18]};
  const float* gbe[3] = {(const float*)d_in[7],(const float*)d_in[13],(const float*)d_in[19]};
  const float* demb_W = (const float*)d_in[20]; const float* demb_b = (const float*)d_in[21];
  const float* gatW[2]  = {(const float*)d_in[22],(const float*)d_in[26]};
  const float* gatAS[2] = {(const float*)d_in[23],(const float*)d_in[27]};
  const float* gatAD[2] = {(const float*)d_in[24],(const float*)d_in[28]};
  const float* gatB[2]  = {(const float*)d_in[25],(const float*)d_in[29]};
  const float* cembW1 = (const float*)d_in[30]; const float* cembb1 = (const float*)d_in[31];
  const float* cembW2 = (const float*)d_in[32]; const float* cembb2 = (const float*)d_in[33];
  const float* regW1 = (const float*)d_in[34]; const float* regb1 = (const float*)d_in[35];
  const float* regW2 = (const float*)d_in[36]; const float* regb2 = (const float*)d_in[37];
  const float* regW3 = (const float*)d_in[38]; const float* regb3 = (const float*)d_in[39];
  const int* dei = (const int*)d_in[40];
  const int* ei0 = (const int*)d_in[42];
  const int* ei1 = (const int*)d_in[43];
  const int* cl0 = (const int*)d_in[44];
  const int* cl1 = (const int*)d_in[45];
  const int *dsrc = dei, *ddst = dei + Ed;
  const int *src0 = ei0, *dst0 = ei0 + Ec0;
  const int *src1 = ei1, *dst1 = ei1 + Ec1;
  float* out = (float*)d_out;

  // ---- workspace layout ----
  char* base = (char*)d_ws; size_t off = 0;
  auto AL = [&](size_t bytes)->char* { char* p = base + off; off = (off + bytes + 255) & ~(size_t)255; return p; };
  float* h_cat   = (float*)AL((size_t)512*384*4);
  float* t1      = (float*)AL((size_t)512*384*4);
  float* t2      = (float*)AL((size_t)512*384*4);
  float* xd      = (float*)AL((size_t)512*384*4);
  float* cembh   = (float*)AL((size_t)512*1024*4);
  float* pooled1 = (float*)AL((size_t)nc1*16*4);
  float* pooled2 = (float*)AL((size_t)nc2*16*4);
  float* stats   = (float*)AL(256*4);
  float* bparts  = (float*)AL((size_t)64*256*4);
  int*   btot    = (int*)AL(512*4);
  char*  S       = base + off;
  if (ws_size < off + (size_t)56*1024*1024) return;

  dim3 b256(256);
  auto NB = [&](long total) { return dim3((unsigned)((total + 255) / 256)); };
  auto BN = [&](const float* x, int xs, float* y, int ys, int rows, int C,
                const float* g, const float* be) {
    k_bn_stats_p<<<dim3(64), b256, 0, stream>>>(x, rows, C, bparts);
    k_bn_fin<<<dim3(1), dim3(C), 0, stream>>>(bparts, 64, C, 1.f/rows, stats);
    k_bn_apply<<<NB((long)rows*C), b256, 0, stream>>>(x, xs, y, ys, stats, g, be, rows*C, C);
  };

  // ================= DRUG BRANCH =================
  {
    size_t so = 0;
    auto SA = [&](size_t bytes)->char* { char* p = S + so; so = (so + bytes + 255) & ~(size_t)255; return p; };
    float* reps = (float*)SA((size_t)nd*384*4);
    float* xin  = (float*)SA((size_t)nd*128*4);
    float* hbuf = (float*)SA((size_t)nd*128*4);
    float* W1p  = (float*)SA((size_t)96*128*4);
    int* degD = (int*)SA((size_t)nd*4);
    int* rowD = (int*)SA(((size_t)nd+1)*4);
    int* csrD = (int*)SA((size_t)Ed*4);

    hipMemsetAsync(degD, 0, (size_t)nd*4, stream);
    k_deg<<<NB(Ed), b256, 0, stream>>>(ddst, Ed, 0, degD);
    k_scan_block<<<dim3(nd/1024), b256, 0, stream>>>(degD, nd, rowD, btot);
    k_scan_tot<<<1, 512, 0, stream>>>(btot, nd/1024);
    k_scan_add<<<NB(nd), b256, 0, stream>>>(rowD, btot, nd, Ed);
    hipMemsetAsync(degD, 0, (size_t)nd*4, stream);
    k_fill<<<NB(Ed), b256, 0, stream>>>(dsrc, ddst, Ed, 0, degD, rowD, csrD);

    k_pad<<<NB(96*128), b256, 0, stream>>>(gW1[0], 77, 128, W1p, 96, 128);

    const float* xsrc = drug_x; int xs = 77, F = 77, ds = 96;
    for (int L = 0; L < 3; ++L) {
      k_gin_gather<<<NB((long)nd*ds), b256, 0, stream>>>(rowD, csrD, xsrc, xs, F, xin, ds, nd);
      const float* W1 = (L == 0) ? W1p : gW1[L];
      int K1 = (L == 0) ? 96 : 128;
      k_gemm<1,0><<<dim3(2,320,1), b256, 0, stream>>>(xin, ds, W1, 128, gb1[L], hbuf, 128, K1, 0);
      k_gemm<1,0><<<dim3(2,320,1), b256, 0, stream>>>(hbuf, 128, gW2[L], 128, gb2[L], xin, 128, 128, 0);
      BN(xin, 128, reps + L*128, 384, nd, 128, gg[L], gbe[L]);
      xsrc = reps + L*128; xs = 384; F = 128; ds = 128;
    }
    k_drug_pool<<<dim3(512), dim3(384), 0, stream>>>(reps, xd);
    k_gemm<1,0><<<dim3(2,8,1), b256, 0, stream>>>(xd, 384, demb_W, 128, demb_b, h_cat, 384, 384, 0);
  }

  // ================= CELL BRANCH: two fused per-batch GAT layers =================
  k_gat_lds<706,512,3,8000,0><<<dim3(512), dim3(512), 0, stream>>>(
      cell_x, src0, dst0, Ec0/512, gatW[0], gatAS[0], gatAD[0], gatB[0], cl0, pooled1);
  BN(pooled1, 16, pooled1, 16, nc1, 16, nullptr, nullptr);

  k_gat_lds<512,400,16,8000,1><<<dim3(512), dim3(512), 0, stream>>>(
      pooled1, src1, dst1, Ec1, gatW[1], gatAS[1], gatAD[1], gatB[1], cl1, pooled2);
  BN(pooled2, 16, pooled2, 16, nc2, 16, nullptr, nullptr);

  // ================= cell embedding MLP (split-K via partials, no atomics) =======
  float* parts = (float*)S;   // drug scratch no longer needed
  k_gemm<0,1><<<dim3(16,8,8), b256, 0, stream>>>(pooled2, 6400, cembW1, 1024, nullptr,
                                                 parts, 1024, 800, (long)512*1024);
  k_reduce<1><<<NB((long)512*1024), b256, 0, stream>>>(parts, 8, (long)512*1024, cembb1,
                                                       cembh, 1024, 512, 1024);
  k_gemm<0,1><<<dim3(4,8,8), b256, 0, stream>>>(cembh, 1024, cembW2, 256, nullptr,
                                                parts, 256, 128, (long)512*256);
  k_reduce<1><<<NB((long)512*256), b256, 0, stream>>>(parts, 8, (long)512*256, cembb2,
                                                      h_cat + 128, 384, 512, 256);

  // ================= regressor =================
  k_gemm<0,1><<<dim3(6,8,4), b256, 0, stream>>>(h_cat, 384, regW1, 384, nullptr,
                                                parts, 384, 96, (long)512*384);
  k_reduce<2><<<NB((long)512*384), b256, 0, stream>>>(parts, 4, (long)512*384, regb1,
                                                      t1, 384, 512, 384);
  k_gemm<0,1><<<dim3(6,8,4), b256, 0, stream>>>(t1, 384, regW2, 384, nullptr,
                                                parts, 384, 96, (long)512*384);
  k_reduce<2><<<NB((long)512*384), b256, 0, stream>>>(parts, 4, (long)512*384, regb2,
                                                      t2, 384, 512, 384);
  k_gemv_out<<<dim3(512), dim3(64), 0, stream>>>(t2, regW3, regb3, out);
}

// Round 7
// 868.434 us; speedup vs baseline: 1.9424x; 1.0424x over previous
//
#include <hip/hip_runtime.h>
#include <math.h>

// ===================== small utility kernels =====================

__global__ void k_pad(const float* __restrict__ src, int sr, int sc,
                      float* __restrict__ dst, int dr, int dc) {
  int t = blockIdx.x*blockDim.x + threadIdx.x;
  if (t >= dr*dc) return;
  int r = t/dc, c = t - r*dc;
  dst[t] = (r < sr && c < sc) ? src[r*sc + c] : 0.f;
}

__global__ void k_deg(const int* __restrict__ dst, int E, int nsl, int* __restrict__ deg) {
  int t = blockIdx.x*blockDim.x + threadIdx.x;
  if (t >= E + nsl) return;
  int d = (t < E) ? dst[t] : (t - E);
  atomicAdd(&deg[d], 1);
}

__global__ __launch_bounds__(256)
void k_scan_block(const int* __restrict__ deg, int n, int* __restrict__ out, int* __restrict__ btot) {
  __shared__ int sh[256];
  int tid = threadIdx.x;
  int base = blockIdx.x*1024 + tid*4;
  int v0 = (base+0<n)?deg[base+0]:0;
  int v1 = (base+1<n)?deg[base+1]:0;
  int v2 = (base+2<n)?deg[base+2]:0;
  int v3 = (base+3<n)?deg[base+3]:0;
  int s = v0+v1+v2+v3;
  sh[tid] = s; __syncthreads();
  for (int o = 1; o < 256; o <<= 1) {
    int t = (tid >= o) ? sh[tid-o] : 0;
    __syncthreads();
    sh[tid] += t;
    __syncthreads();
  }
  if (tid == 255) btot[blockIdx.x] = sh[255];
  int run = sh[tid] - s;
  if (base+0<n) { out[base+0]=run; run+=v0; }
  if (base+1<n) { out[base+1]=run; run+=v1; }
  if (base+2<n) { out[base+2]=run; run+=v2; }
  if (base+3<n) { out[base+3]=run; run+=v3; }
}

__global__ __launch_bounds__(512)
void k_scan_tot(int* __restrict__ btot, int nb) {
  __shared__ int sh[512];
  int tid = threadIdx.x;
  int v = (tid < nb) ? btot[tid] : 0;
  sh[tid] = v; __syncthreads();
  for (int o = 1; o < 512; o <<= 1) {
    int t = (tid >= o) ? sh[tid-o] : 0;
    __syncthreads();
    sh[tid] += t;
    __syncthreads();
  }
  if (tid < nb) btot[tid] = sh[tid] - v;
}

__global__ void k_scan_add(int* __restrict__ rowptr, const int* __restrict__ btot, int n, int total) {
  int t = blockIdx.x*blockDim.x + threadIdx.x;
  if (t < n) rowptr[t] += btot[t >> 10];
  if (t == 0) rowptr[n] = total;
}

__global__ void k_fill(const int* __restrict__ src, const int* __restrict__ dst, int E, int nsl,
                       int* __restrict__ cursor, const int* __restrict__ rowptr, int* __restrict__ csr) {
  int t = blockIdx.x*blockDim.x + threadIdx.x;
  if (t >= E + nsl) return;
  int s, d;
  if (t < E) { s = src[t]; d = dst[t]; } else { s = t - E; d = s; }
  int slot = rowptr[d] + atomicAdd(&cursor[d], 1);
  csr[slot] = s;
}

// ===================== GIN (drug) =====================
__global__ void k_gin_gather(const int* __restrict__ rowptr, const int* __restrict__ csr,
                             const float* __restrict__ x, int xs, int F,
                             float* __restrict__ xin, int ds, int n) {
  int t = blockIdx.x*blockDim.x + threadIdx.x;
  if (t >= n*ds) return;
  int d = t/ds, f = t - d*ds;
  if (f >= F) { xin[t] = 0.f; return; }
  float acc = x[(size_t)d*xs + f];
  int e1 = rowptr[d+1];
  for (int j = rowptr[d]; j < e1; ++j) acc += x[(size_t)csr[j]*xs + f];
  xin[t] = acc;
}

__global__ __launch_bounds__(384)
void k_drug_pool(const float* __restrict__ reps, float* __restrict__ xd) {
  int b = blockIdx.x, c = threadIdx.x;
  float m = -3.0e38f;
  const float* p = reps + (size_t)b*40*384 + c;
  for (int i = 0; i < 40; ++i) m = fmaxf(m, p[(size_t)i*384]);
  xd[(size_t)b*384 + c] = m;
}

// ===================== GEMM (f32, tiled 64x64; PART=split-K partial store) ==========
template<int ACT, int PART>   // ACT: 0 none, 1 relu, 2 elu (non-partial path only)
__global__ __launch_bounds__(256)
void k_gemm(const float* __restrict__ A, int lda,
            const float* __restrict__ B, int ldb,
            const float* __restrict__ bias,
            float* __restrict__ C, int ldc, int Kchunk, long pstride) {
  __shared__ __align__(16) float As[32][68];
  __shared__ __align__(16) float Bs[32][68];
  const int tid = threadIdx.x;
  const int tx = tid & 15, ty = tid >> 4;
  const int row0 = blockIdx.y << 6, col0 = blockIdx.x << 6;
  const int kb = blockIdx.z * Kchunk;
  if (PART) C += (size_t)blockIdx.z * pstride;
  float acc[4][4] = {{0.f}};
  for (int k0 = 0; k0 < Kchunk; k0 += 32) {
#pragma unroll
    for (int i = 0; i < 2; ++i) {
      int idx = tid + (i << 8);
      int r = idx >> 3, c = (idx & 7) << 2;
      float4 v = *(const float4*)(A + (size_t)(row0 + r)*lda + (kb + k0 + c));
      As[c+0][r]=v.x; As[c+1][r]=v.y; As[c+2][r]=v.z; As[c+3][r]=v.w;
    }
#pragma unroll
    for (int i = 0; i < 2; ++i) {
      int idx = tid + (i << 8);
      int r = idx >> 4, c = (idx & 15) << 2;
      *(float4*)&Bs[r][c] = *(const float4*)(B + (size_t)(kb + k0 + r)*ldb + (col0 + c));
    }
    __syncthreads();
#pragma unroll
    for (int kk = 0; kk < 32; ++kk) {
      float4 av = *(const float4*)&As[kk][ty << 2];
      float4 bv = *(const float4*)&Bs[kk][tx << 2];
      acc[0][0]=fmaf(av.x,bv.x,acc[0][0]); acc[0][1]=fmaf(av.x,bv.y,acc[0][1]);
      acc[0][2]=fmaf(av.x,bv.z,acc[0][2]); acc[0][3]=fmaf(av.x,bv.w,acc[0][3]);
      acc[1][0]=fmaf(av.y,bv.x,acc[1][0]); acc[1][1]=fmaf(av.y,bv.y,acc[1][1]);
      acc[1][2]=fmaf(av.y,bv.z,acc[1][2]); acc[1][3]=fmaf(av.y,bv.w,acc[1][3]);
      acc[2][0]=fmaf(av.z,bv.x,acc[2][0]); acc[2][1]=fmaf(av.z,bv.y,acc[2][1]);
      acc[2][2]=fmaf(av.z,bv.z,acc[2][2]); acc[2][3]=fmaf(av.z,bv.w,acc[2][3]);
      acc[3][0]=fmaf(av.w,bv.x,acc[3][0]); acc[3][1]=fmaf(av.w,bv.y,acc[3][1]);
      acc[3][2]=fmaf(av.w,bv.z,acc[3][2]); acc[3][3]=fmaf(av.w,bv.w,acc[3][3]);
    }
    __syncthreads();
  }
#pragma unroll
  for (int i = 0; i < 4; ++i) {
    int r = row0 + (ty<<2) + i, c = col0 + (tx<<2);
    float4 v = make_float4(acc[i][0], acc[i][1], acc[i][2], acc[i][3]);
    if (!PART) {
      if (bias) { v.x += bias[c]; v.y += bias[c+1]; v.z += bias[c+2]; v.w += bias[c+3]; }
      if (ACT == 1) { v.x=fmaxf(v.x,0.f); v.y=fmaxf(v.y,0.f); v.z=fmaxf(v.z,0.f); v.w=fmaxf(v.w,0.f); }
      else if (ACT == 2) {
        v.x = v.x>0.f?v.x:expm1f(v.x); v.y = v.y>0.f?v.y:expm1f(v.y);
        v.z = v.z>0.f?v.z:expm1f(v.z); v.w = v.w>0.f?v.w:expm1f(v.w);
      }
    }
    *(float4*)(C + (size_t)r*ldc + c) = v;
  }
}

// sum split-K partials + bias + activation
template<int ACT>
__global__ void k_reduce(const float* __restrict__ parts, int np, long pstride,
                         const float* __restrict__ bias,
                         float* __restrict__ out, int ldo, int M, int N) {
  int t = blockIdx.x*blockDim.x + threadIdx.x;
  if (t >= M*N) return;
  int r = t / N, c = t - r*N;
  float s = 0.f;
  for (int z = 0; z < np; ++z) s += parts[(size_t)z*pstride + t];
  s += bias[c];
  if (ACT == 1) s = fmaxf(s, 0.f);
  else if (ACT == 2) s = s > 0.f ? s : expm1f(s);
  out[(size_t)r*ldo + c] = s;
}

// ===================== BatchNorm (no float atomics) =====================
__global__ __launch_bounds__(256)
void k_bn_stats_p(const float* __restrict__ x, int rows, int C, float* __restrict__ parts) {
  __shared__ float sh[256], sh2[256];
  int tid = threadIdx.x;
  int c = tid % C;
  int rpb = 256 / C;
  int r0 = blockIdx.x*rpb + tid / C;
  int rstep = gridDim.x * rpb;
  float s = 0.f, s2 = 0.f;
  for (int r = r0; r < rows; r += rstep) {
    float v = x[(size_t)r*C + c];
    s += v; s2 = fmaf(v, v, s2);
  }
  sh[tid] = s; sh2[tid] = s2; __syncthreads();
  for (int o = 128; o >= C; o >>= 1) {
    if (tid < o) { sh[tid] += sh[tid+o]; sh2[tid] += sh2[tid+o]; }
    __syncthreads();
  }
  if (tid < C) { parts[blockIdx.x*2*C + tid] = sh[tid]; parts[blockIdx.x*2*C + C + tid] = sh2[tid]; }
}

__global__ void k_bn_fin(const float* __restrict__ parts, int nb, int C, float invn,
                         float* __restrict__ stats) {
  int t = threadIdx.x;
  if (t >= C) return;
  float s = 0.f, s2 = 0.f;
  for (int z = 0; z < nb; ++z) { s += parts[z*2*C + t]; s2 += parts[z*2*C + C + t]; }
  float mu = s * invn;
  float var = fmaxf(s2*invn - mu*mu, 0.f);
  stats[t] = mu;
  stats[C + t] = rsqrtf(var + 1e-5f);
}

__global__ void k_bn_apply(const float* __restrict__ x, int xs,
                           float* __restrict__ y, int ys,
                           const float* __restrict__ stats,
                           const float* __restrict__ g, const float* __restrict__ be,
                           int total, int C) {
  int t = blockIdx.x*blockDim.x + threadIdx.x;
  if (t >= total) return;
  int c = t % C;
  int r = t / C;
  float v = (x[(size_t)r*xs + c] - stats[c]) * stats[C + c];
  if (g) v = fmaf(v, g[c], be[c]);
  y[(size_t)r*ys + c] = v;
}

// ===================== fused per-batch GAT layer (2 blocks/CU) =====================
// Block-diagonal graphs; one workgroup per batch item. LDS < 80KB so 2 WG/CU:
//  - no sew: exp(leaky(sss+ssd)) recomputed in the gather (VALU was 81% idle)
//  - no spool: cluster max-pool via native global int atomicMax (values >= 0,
//    target zeroed beforehand, L2-resident, ~1.4 nodes/cluster contention)
//  - sh padded to stride 17 (was 2.5M LDS bank conflicts at stride 16)
//  - gather edge loop unrolled x2 (two independent scsr->sss/sh chains)
template<int NODES, int NPOOL, int KIN, int MAXE, int SORTED>
__global__ __launch_bounds__(512, 4)
void k_gat_lds(const float* __restrict__ x,
               const int* __restrict__ esrc, const int* __restrict__ edst, int Earg,
               const float* __restrict__ W, const float* __restrict__ as_,
               const float* __restrict__ ad_, const float* __restrict__ bias,
               const int* __restrict__ cluster,
               float* __restrict__ pooled) {
  __shared__ float sh[NODES*17];
  __shared__ unsigned short scsr[MAXE];
  __shared__ float sss[NODES], ssd[NODES];
  __shared__ int srow[NODES+1];
  __shared__ float sWl[KIN*16 + 16];
  __shared__ float sas[16], sad[16];
  __shared__ int schunk[32];
  __shared__ int sr2[2];
  const int b = blockIdx.x;
  const int tid = threadIdx.x;
  const int nbase = b*NODES;

  if (tid < KIN*16) sWl[tid] = W[tid];
  if (tid >= 64 && tid < 80)  sWl[KIN*16 + tid-64] = bias[tid-64];
  if (tid >= 80 && tid < 96)  sas[tid-80] = as_[tid-80];
  if (tid >= 96 && tid < 112) sad[tid-96] = ad_[tid-96];
  if (SORTED && tid == 0) {
    int a = 0, c = Earg;
    while (a < c) { int m = (a+c) >> 1; if (esrc[m] < nbase) a = m+1; else c = m; }
    sr2[0] = a;
    c = Earg;
    int nend = nbase + NODES;
    while (a < c) { int m = (a+c) >> 1; if (esrc[m] < nend) a = m+1; else c = m; }
    sr2[1] = a;
  }
  for (int i = tid; i <= NODES; i += 512) srow[i] = 0;
  __syncthreads();

  int e0, Eblk;
  if (SORTED) { e0 = sr2[0]; Eblk = sr2[1] - sr2[0]; }
  else        { e0 = b*Earg; Eblk = Earg; }

  // (a) degree count (native int LDS atomics)
  for (int e = tid; e < Eblk; e += 512) atomicAdd(&srow[(edst[e0+e] - nbase) + 1], 1);
  // (b) h = x@W (lane-shuffle x broadcast); ssrc/sdst via 16-lane reduce
  for (int i = tid; i < NODES*16; i += 512) {
    int n = i >> 4, f = i & 15;
    const float* xp = x + (size_t)(nbase + n)*KIN;
    float xq = (f < KIN) ? xp[f] : 0.f;
    float hv = 0.f;
#pragma unroll
    for (int j = 0; j < KIN; ++j) hv = fmaf(__shfl(xq, j, 16), sWl[j*16 + f], hv);
    sh[n*17 + f] = hv;
    float s1 = hv * sas[f], s2 = hv * sad[f];
#pragma unroll
    for (int m = 8; m >= 1; m >>= 1) { s1 += __shfl_xor(s1, m); s2 += __shfl_xor(s2, m); }
    if (f == 0) { sss[n] = s1; ssd[n] = s2; }
  }
  __syncthreads();

  // (c) chunked prefix scan: srow[n] = start offset of node n
  constexpr int NC = 32, CS = (NODES + NC - 1) / NC;
  if (tid < NC) {
    int run = 0, lo = tid*CS, hi = (tid+1)*CS < NODES ? (tid+1)*CS : NODES;
    for (int i = lo; i < hi; ++i) { run += srow[i+1]; srow[i+1] = run; }
    schunk[tid] = run;
  }
  __syncthreads();
  if (tid == 0) { int base = 0; for (int c = 0; c < NC; ++c) { int t2 = schunk[c]; schunk[c] = base; base += t2; } }
  __syncthreads();
  for (int i = tid; i < NODES; i += 512) srow[i+1] += schunk[i/CS];
  __syncthreads();

  // (d) scatter src into CSR slots; srow[d] is the live cursor
  for (int e = tid; e < Eblk; e += 512) {
    int s = esrc[e0+e] - nbase, d = edst[e0+e] - nbase;
    int slot = atomicAdd(&srow[d], 1);
    scsr[slot] = (unsigned short)s;
  }
  __syncthreads();
  // post-scatter: srow[n] = end(n) = start(n+1); start(0) = 0

  // (e) gather: 16 lanes/node, register accumulation, exp recomputed per edge
  {
    const int lane = tid & 15, grp = tid >> 4;
    for (int n = grp; n < NODES; n += 32) {
      float sdn = ssd[n];
      float ls = sss[n] + sdn;
      ls = (ls > 0.f) ? ls : 0.2f*ls;
      float exs = __expf(ls);                        // self-loop
      float accv = exs * sh[n*17 + lane], sum = exs;
      int j = (n > 0) ? srow[n-1] : 0, j1 = srow[n];
      for (; j + 2 <= j1; j += 2) {
        int s0 = scsr[j], s1 = scsr[j+1];
        float l0 = sss[s0] + sdn, l1 = sss[s1] + sdn;
        float h0 = sh[s0*17 + lane], h1 = sh[s1*17 + lane];
        l0 = (l0 > 0.f) ? l0 : 0.2f*l0;
        l1 = (l1 > 0.f) ? l1 : 0.2f*l1;
        float ex0 = __expf(l0), ex1 = __expf(l1);
        accv = fmaf(ex0, h0, accv); sum += ex0;
        accv = fmaf(ex1, h1, accv); sum += ex1;
      }
      if (j < j1) {
        int s0 = scsr[j];
        float l0 = sss[s0] + sdn;
        l0 = (l0 > 0.f) ? l0 : 0.2f*l0;
        float ex0 = __expf(l0);
        accv = fmaf(ex0, sh[s0*17 + lane], accv); sum += ex0;
      }
      float v = fmaf(accv, 1.f/sum, sWl[KIN*16 + lane]);
      v = fmaxf(v, 0.f);
      atomicMax((int*)pooled + (size_t)cluster[nbase + n]*16 + lane, __float_as_int(v));
    }
  }
}

// ===================== final GEMV =====================
__global__ __launch_bounds__(64)
void k_gemv_out(const float* __restrict__ A, const float* __restrict__ w,
                const float* __restrict__ b, float* __restrict__ out) {
  int r = blockIdx.x, l = threadIdx.x;
  float s = 0.f;
  for (int k = l; k < 384; k += 64) s = fmaf(A[(size_t)r*384 + k], w[k], s);
#pragma unroll
  for (int o = 32; o > 0; o >>= 1) s += __shfl_down(s, o);
  if (l == 0) out[r] = s + b[0];
}

// ===================== host orchestration =====================
extern "C" void kernel_launch(void* const* d_in, const int* in_sizes, int n_in,
                              void* d_out, int out_size, void* d_ws, size_t ws_size,
                              hipStream_t stream) {
  (void)n_in; (void)out_size;
  const int B = 512;
  const int nd  = B*40;
  const int nc1 = B*512;
  const int nc2 = B*400;
  const int Ed  = in_sizes[40]/2;
  const int Ec0 = in_sizes[42]/2;
  const int Ec1 = in_sizes[43]/2;

  const float* drug_x = (const float*)d_in[0];
  const float* cell_x = (const float*)d_in[1];
  const float* gW1[3] = {(const float*)d_in[2],(const float*)d_in[8],(const float*)d_in[14]};
  const float* gb1[3] = {(const float*)d_in[3],(const float*)d_in[9],(const float*)d_in[15]};
  const float* gW2[3] = {(const float*)d_in[4],(const float*)d_in[10],(const float*)d_in[16]};
  const float* gb2[3] = {(const float*)d_in[5],(const float*)d_in[11],(const float*)d_in[17]};
  const float* gg [3] = {(const float*)d_in[6],(const float*)d_in[12],(const float*)d_in[18]};
  const float* gbe[3] = {(const float*)d_in[7],(const float*)d_in[13],(const float*)d_in[19]};
  const float* demb_W = (const float*)d_in[20]; const float* demb_b = (const float*)d_in[21];
  const float* gatW[2]  = {(const float*)d_in[22],(const float*)d_in[26]};
  const float* gatAS[2] = {(const float*)d_in[23],(const float*)d_in[27]};
  const float* gatAD[2] = {(const float*)d_in[24],(const float*)d_in[28]};
  const float* gatB[2]  = {(const float*)d_in[25],(const float*)d_in[29]};
  const float* cembW1 = (const float*)d_in[30]; const float* cembb1 = (const float*)d_in[31];
  const float* cembW2 = (const float*)d_in[32]; const float* cembb2 = (const float*)d_in[33];
  const float* regW1 = (const float*)d_in[34]; const float* regb1 = (const float*)d_in[35];
  const float* regW2 = (const float*)d_in[36]; const float* regb2 = (const float*)d_in[37];
  const float* regW3 = (const float*)d_in[38]; const float* regb3 = (const float*)d_in[39];
  const int* dei = (const int*)d_in[40];
  const int* ei0 = (const int*)d_in[42];
  const int* ei1 = (const int*)d_in[43];
  const int* cl0 = (const int*)d_in[44];
  const int* cl1 = (const int*)d_in[45];
  const int *dsrc = dei, *ddst = dei + Ed;
  const int *src0 = ei0, *dst0 = ei0 + Ec0;
  const int *src1 = ei1, *dst1 = ei1 + Ec1;
  float* out = (float*)d_out;

  // ---- workspace layout ----
  char* base = (char*)d_ws; size_t off = 0;
  auto AL = [&](size_t bytes)->char* { char* p = base + off; off = (off + bytes + 255) & ~(size_t)255; return p; };
  float* h_cat   = (float*)AL((size_t)512*384*4);
  float* t1      = (float*)AL((size_t)512*384*4);
  float* t2      = (float*)AL((size_t)512*384*4);
  float* xd      = (float*)AL((size_t)512*384*4);
  float* cembh   = (float*)AL((size_t)512*1024*4);
  float* pooled1 = (float*)AL((size_t)nc1*16*4);
  float* pooled2 = (float*)AL((size_t)nc2*16*4);
  float* stats   = (float*)AL(256*4);
  float* bparts  = (float*)AL((size_t)64*256*4);
  int*   btot    = (int*)AL(512*4);
  char*  S       = base + off;
  if (ws_size < off + (size_t)56*1024*1024) return;

  dim3 b256(256);
  auto NB = [&](long total) { return dim3((unsigned)((total + 255) / 256)); };
  auto BN = [&](const float* x, int xs, float* y, int ys, int rows, int C,
                const float* g, const float* be) {
    k_bn_stats_p<<<dim3(64), b256, 0, stream>>>(x, rows, C, bparts);
    k_bn_fin<<<dim3(1), dim3(C), 0, stream>>>(bparts, 64, C, 1.f/rows, stats);
    k_bn_apply<<<NB((long)rows*C), b256, 0, stream>>>(x, xs, y, ys, stats, g, be, rows*C, C);
  };

  // ================= DRUG BRANCH =================
  {
    size_t so = 0;
    auto SA = [&](size_t bytes)->char* { char* p = S + so; so = (so + bytes + 255) & ~(size_t)255; return p; };
    float* reps = (float*)SA((size_t)nd*384*4);
    float* xin  = (float*)SA((size_t)nd*128*4);
    float* hbuf = (float*)SA((size_t)nd*128*4);
    float* W1p  = (float*)SA((size_t)96*128*4);
    int* degD = (int*)SA((size_t)nd*4);
    int* rowD = (int*)SA(((size_t)nd+1)*4);
    int* csrD = (int*)SA((size_t)Ed*4);

    hipMemsetAsync(degD, 0, (size_t)nd*4, stream);
    k_deg<<<NB(Ed), b256, 0, stream>>>(ddst, Ed, 0, degD);
    k_scan_block<<<dim3(nd/1024), b256, 0, stream>>>(degD, nd, rowD, btot);
    k_scan_tot<<<1, 512, 0, stream>>>(btot, nd/1024);
    k_scan_add<<<NB(nd), b256, 0, stream>>>(rowD, btot, nd, Ed);
    hipMemsetAsync(degD, 0, (size_t)nd*4, stream);
    k_fill<<<NB(Ed), b256, 0, stream>>>(dsrc, ddst, Ed, 0, degD, rowD, csrD);

    k_pad<<<NB(96*128), b256, 0, stream>>>(gW1[0], 77, 128, W1p, 96, 128);

    const float* xsrc = drug_x; int xs = 77, F = 77, ds = 96;
    for (int L = 0; L < 3; ++L) {
      k_gin_gather<<<NB((long)nd*ds), b256, 0, stream>>>(rowD, csrD, xsrc, xs, F, xin, ds, nd);
      const float* W1 = (L == 0) ? W1p : gW1[L];
      int K1 = (L == 0) ? 96 : 128;
      k_gemm<1,0><<<dim3(2,320,1), b256, 0, stream>>>(xin, ds, W1, 128, gb1[L], hbuf, 128, K1, 0);
      k_gemm<1,0><<<dim3(2,320,1), b256, 0, stream>>>(hbuf, 128, gW2[L], 128, gb2[L], xin, 128, 128, 0);
      BN(xin, 128, reps + L*128, 384, nd, 128, gg[L], gbe[L]);
      xsrc = reps + L*128; xs = 384; F = 128; ds = 128;
    }
    k_drug_pool<<<dim3(512), dim3(384), 0, stream>>>(reps, xd);
    k_gemm<1,0><<<dim3(2,8,1), b256, 0, stream>>>(xd, 384, demb_W, 128, demb_b, h_cat, 384, 384, 0);
  }

  // ================= CELL BRANCH: two fused per-batch GAT layers =================
  hipMemsetAsync(pooled1, 0, (size_t)nc1*16*4, stream);
  k_gat_lds<706,512,3,8000,0><<<dim3(512), dim3(512), 0, stream>>>(
      cell_x, src0, dst0, Ec0/512, gatW[0], gatAS[0], gatAD[0], gatB[0], cl0, pooled1);
  BN(pooled1, 16, pooled1, 16, nc1, 16, nullptr, nullptr);

  hipMemsetAsync(pooled2, 0, (size_t)nc2*16*4, stream);
  k_gat_lds<512,400,16,8000,1><<<dim3(512), dim3(512), 0, stream>>>(
      pooled1, src1, dst1, Ec1, gatW[1], gatAS[1], gatAD[1], gatB[1], cl1, pooled2);
  BN(pooled2, 16, pooled2, 16, nc2, 16, nullptr, nullptr);

  // ================= cell embedding MLP (split-K via partials, no atomics) =======
  float* parts = (float*)S;   // drug scratch no longer needed
  k_gemm<0,1><<<dim3(16,8,8), b256, 0, stream>>>(pooled2, 6400, cembW1, 1024, nullptr,
                                                 parts, 1024, 800, (long)512*1024);
  k_reduce<1><<<NB((long)512*1024), b256, 0, stream>>>(parts, 8, (long)512*1024, cembb1,
                                                       cembh, 1024, 512, 1024);
  k_gemm<0,1><<<dim3(4,8,8), b256, 0, stream>>>(cembh, 1024, cembW2, 256, nullptr,
                                                parts, 256, 128, (long)512*256);
  k_reduce<1><<<NB((long)512*256), b256, 0, stream>>>(parts, 8, (long)512*256, cembb2,
                                                      h_cat + 128, 384, 512, 256);

  // ================= regressor =================
  k_gemm<0,1><<<dim3(6,8,4), b256, 0, stream>>>(h_cat, 384, regW1, 384, nullptr,
                                                parts, 384, 96, (long)512*384);
  k_reduce<2><<<NB((long)512*384), b256, 0, stream>>>(parts, 4, (long)512*384, regb1,
                                                      t1, 384, 512, 384);
  k_gemm<0,1><<<dim3(6,8,4), b256, 0, stream>>>(t1, 384, regW2, 384, nullptr,
                                                parts, 384, 96, (long)512*384);
  k_reduce<2><<<NB((long)512*384), b256, 0, stream>>>(parts, 4, (long)512*384, regb2,
                                                      t2, 384, 512, 384);
  k_gemv_out<<<dim3(512), dim3(64), 0, stream>>>(t2, regW3, regb3, out);
}